// Round 1
// baseline (376.489 us; speedup 1.0000x reference)
//
#include <hip/hip_runtime.h>

#define NGRAPH 16384
#define NNODE  32
#define EMB    64
#define HIDDIM 2048
#define NTOT   (NGRAPH * NNODE)
#define ETOT   4194304      // NTOT * 8
#define EPG    256          // edges per graph (contiguous block per graph)

typedef __attribute__((ext_vector_type(8))) short bf16x8_t;
typedef __attribute__((ext_vector_type(8))) unsigned short u16x8_t;
typedef __attribute__((ext_vector_type(4))) float f32x4_t;

__device__ __forceinline__ unsigned short f2bf(float v) {
  // round-to-nearest-even f32 -> bf16 bits
  unsigned int u = __float_as_uint(v);
  u += 0x7fffu + ((u >> 16) & 1u);
  return (unsigned short)(u >> 16);
}

// ---------------------------------------------------------------------------
// Kernel 1: W1 (fp32 [2048][2048], row-major [out][in]) -> bf16
// ---------------------------------------------------------------------------
__global__ __launch_bounds__(256) void cvt_w1(const float* __restrict__ W,
                                              unsigned short* __restrict__ Wb) {
  const int i = blockIdx.x * 256 + threadIdx.x;   // 0..524287, 8 floats each
  const float4* p = (const float4*)W;
  const float4 a = p[2 * i];
  const float4 b = p[2 * i + 1];
  u16x8_t o;
  o[0] = f2bf(a.x); o[1] = f2bf(a.y); o[2] = f2bf(a.z); o[3] = f2bf(a.w);
  o[4] = f2bf(b.x); o[5] = f2bf(b.y); o[6] = f2bf(b.z); o[7] = f2bf(b.w);
  *((u16x8_t*)Wb + i) = o;
}

// ---------------------------------------------------------------------------
// Kernel 2: fused GCNConv + ReLU, one block per graph, bf16 output (A matrix)
// out[n][f] = relu( sum_m adj[n][m]*h[m][f] + bc[f] ),  h = x @ Wc^T
// adj[d][s] = sum_{edges s->d} dinv[s]*dinv[d]  (+ dinv[i]^2 self loop)
// ---------------------------------------------------------------------------
__global__ __launch_bounds__(256) void gcn_kernel(const float* __restrict__ x,
                                                  const float* __restrict__ Wc,
                                                  const float* __restrict__ bc,
                                                  const int* __restrict__ ei,
                                                  unsigned short* __restrict__ abf) {
  __shared__ float xs[NNODE][68];    // pad 68: conflict-free float4 reads
  __shared__ float wst[EMB][68];     // wst[k][f] = Wc[f][k]
  __shared__ float hs[NNODE][68];
  __shared__ float adjm[NNODE][33];
  __shared__ float degs[NNODE];
  __shared__ float dinv[NNODE];

  const int g = blockIdx.x;
  const int t = threadIdx.x;

  // ---- phase 1: stage x, Wc^T, zero adj, init deg (self-loop = 1)
  for (int id = t; id < 512; id += 256) {
    const int nn = id >> 4, c = (id & 15) * 4;
    *(float4*)&xs[nn][c] = *(const float4*)(x + (size_t)g * (NNODE * EMB) + nn * EMB + c);
  }
  for (int i = t; i < EMB * EMB; i += 256) {
    wst[i & 63][i >> 6] = Wc[i];     // Wc[f*64+k] -> wst[k][f]
  }
  for (int i = t; i < NNODE * 33; i += 256) (&adjm[0][0])[i] = 0.0f;
  if (t < NNODE) degs[t] = 1.0f;
  const int sl = ei[(size_t)g * EPG + t] - g * NNODE;                 // src local
  const int dl = ei[(size_t)ETOT + (size_t)g * EPG + t] - g * NNODE;  // dst local
  __syncthreads();

  // ---- phase 2: degree atomics + h = x @ Wc^T (thread: node n, feats f0..f0+7)
  atomicAdd(&degs[dl], 1.0f);

  const int n = t >> 3;
  const int f0 = (t & 7) * 8;
  float a0 = 0, a1 = 0, a2 = 0, a3 = 0, a4 = 0, a5 = 0, a6 = 0, a7 = 0;
  #pragma unroll 8
  for (int k = 0; k < EMB; ++k) {
    const float xv = xs[n][k];
    const float4 w0 = *(const float4*)&wst[k][f0];
    const float4 w1 = *(const float4*)&wst[k][f0 + 4];
    a0 = fmaf(xv, w0.x, a0); a1 = fmaf(xv, w0.y, a1);
    a2 = fmaf(xv, w0.z, a2); a3 = fmaf(xv, w0.w, a3);
    a4 = fmaf(xv, w1.x, a4); a5 = fmaf(xv, w1.y, a5);
    a6 = fmaf(xv, w1.z, a6); a7 = fmaf(xv, w1.w, a7);
  }
  *(float4*)&hs[n][f0]     = make_float4(a0, a1, a2, a3);
  *(float4*)&hs[n][f0 + 4] = make_float4(a4, a5, a6, a7);
  __syncthreads();

  // ---- phase 3: dinv = rsqrt(deg)
  if (t < NNODE) dinv[t] = rsqrtf(degs[t]);
  __syncthreads();

  // ---- phase 4: build normalized adjacency
  atomicAdd(&adjm[dl][sl], dinv[sl] * dinv[dl]);
  if (t < NNODE) atomicAdd(&adjm[t][t], dinv[t] * dinv[t]);
  __syncthreads();

  // ---- phase 5: out = adj @ h + bc, relu, bf16 store (16B per thread)
  a0 = a1 = a2 = a3 = a4 = a5 = a6 = a7 = 0.0f;
  #pragma unroll 4
  for (int m = 0; m < NNODE; ++m) {
    const float av = adjm[n][m];
    const float4 h0 = *(const float4*)&hs[m][f0];
    const float4 h1 = *(const float4*)&hs[m][f0 + 4];
    a0 = fmaf(av, h0.x, a0); a1 = fmaf(av, h0.y, a1);
    a2 = fmaf(av, h0.z, a2); a3 = fmaf(av, h0.w, a3);
    a4 = fmaf(av, h1.x, a4); a5 = fmaf(av, h1.y, a5);
    a6 = fmaf(av, h1.z, a6); a7 = fmaf(av, h1.w, a7);
  }
  const float4 bc0 = *(const float4*)(bc + f0);
  const float4 bc1 = *(const float4*)(bc + f0 + 4);
  u16x8_t o;
  o[0] = f2bf(fmaxf(a0 + bc0.x, 0.0f));
  o[1] = f2bf(fmaxf(a1 + bc0.y, 0.0f));
  o[2] = f2bf(fmaxf(a2 + bc0.z, 0.0f));
  o[3] = f2bf(fmaxf(a3 + bc0.w, 0.0f));
  o[4] = f2bf(fmaxf(a4 + bc1.x, 0.0f));
  o[5] = f2bf(fmaxf(a5 + bc1.y, 0.0f));
  o[6] = f2bf(fmaxf(a6 + bc1.z, 0.0f));
  o[7] = f2bf(fmaxf(a7 + bc1.w, 0.0f));
  *(u16x8_t*)(abf + (size_t)g * HIDDIM + n * EMB + f0) = o;
}

// ---------------------------------------------------------------------------
// Kernel 3: lin1 GEMM  C[16384,2048] = relu(A[16384,2048] @ W1^T + b1), fp32 out
// bf16 MFMA, m97 structure: 128x128 tile, BK=32, 4 waves, global_load_lds w=16
// ---------------------------------------------------------------------------
__global__ __launch_bounds__(256) void lin1_kernel(const unsigned short* __restrict__ A,
                                                   const unsigned short* __restrict__ Bw,
                                                   const float* __restrict__ b1,
                                                   float* __restrict__ C) {
  __shared__ __align__(16) unsigned short As[128 * 32];  // [m][k] linear, 8KB
  __shared__ __align__(16) unsigned short Bs[128 * 32];

  // XCD swizzle (2048 % 8 == 0) + supertile: chunks of 8 bm x 16 bn (~12MB ws)
  const int bid = blockIdx.x;
  const int u = (bid & 7) * 256 + (bid >> 3);
  const int chunk = u >> 7;
  const int local = u & 127;
  const int bm = chunk * 8 + (local & 7);   // 0..127
  const int bn = local >> 3;                // 0..15

  const int t = threadIdx.x;
  const int lane = t & 63;
  const int w = t >> 6;
  const int wr = w >> 1, wc = w & 1;        // wave -> 64x64 quadrant
  const int lrow = lane & 15, lk = lane >> 4;

  // staging: 512 chunks of 16B per tile; chunk c -> row c>>2, k-col (c&3)*8
  const int c0 = w * 128 + lane;
  const int c1 = c0 + 64;
  const unsigned short* gA0 = A  + (size_t)(bm * 128 + (c0 >> 2)) * HIDDIM + (c0 & 3) * 8;
  const unsigned short* gA1 = A  + (size_t)(bm * 128 + (c1 >> 2)) * HIDDIM + (c1 & 3) * 8;
  const unsigned short* gB0 = Bw + (size_t)(bn * 128 + (c0 >> 2)) * HIDDIM + (c0 & 3) * 8;
  const unsigned short* gB1 = Bw + (size_t)(bn * 128 + (c1 >> 2)) * HIDDIM + (c1 & 3) * 8;
  unsigned short* lA0 = As + c0 * 8;
  unsigned short* lA1 = As + c1 * 8;
  unsigned short* lB0 = Bs + c0 * 8;
  unsigned short* lB1 = Bs + c1 * 8;

  f32x4_t acc[4][4];
  #pragma unroll
  for (int i = 0; i < 4; ++i)
    #pragma unroll
    for (int j = 0; j < 4; ++j) acc[i][j] = (f32x4_t){0.f, 0.f, 0.f, 0.f};

  for (int kt = 0; kt < HIDDIM; kt += 32) {
    __builtin_amdgcn_global_load_lds((const __attribute__((address_space(1))) void*)(gA0 + kt),
                                     (__attribute__((address_space(3))) void*)lA0, 16, 0, 0);
    __builtin_amdgcn_global_load_lds((const __attribute__((address_space(1))) void*)(gA1 + kt),
                                     (__attribute__((address_space(3))) void*)lA1, 16, 0, 0);
    __builtin_amdgcn_global_load_lds((const __attribute__((address_space(1))) void*)(gB0 + kt),
                                     (__attribute__((address_space(3))) void*)lB0, 16, 0, 0);
    __builtin_amdgcn_global_load_lds((const __attribute__((address_space(1))) void*)(gB1 + kt),
                                     (__attribute__((address_space(3))) void*)lB1, 16, 0, 0);
    __syncthreads();   // compiler emits vmcnt(0) drain + barrier

    bf16x8_t av[4], bv[4];
    #pragma unroll
    for (int mi = 0; mi < 4; ++mi)
      av[mi] = *(const bf16x8_t*)(As + (wr * 64 + mi * 16 + lrow) * 32 + lk * 8);
    #pragma unroll
    for (int ni = 0; ni < 4; ++ni)
      bv[ni] = *(const bf16x8_t*)(Bs + (wc * 64 + ni * 16 + lrow) * 32 + lk * 8);

    #pragma unroll
    for (int mi = 0; mi < 4; ++mi)
      #pragma unroll
      for (int ni = 0; ni < 4; ++ni)
        acc[mi][ni] = __builtin_amdgcn_mfma_f32_16x16x32_bf16(av[mi], bv[ni], acc[mi][ni], 0, 0, 0);
    __syncthreads();
  }

  // epilogue: + b1, relu, store fp32
  float b1v[4];
  #pragma unroll
  for (int ni = 0; ni < 4; ++ni) b1v[ni] = b1[bn * 128 + wc * 64 + ni * 16 + lrow];

  #pragma unroll
  for (int mi = 0; mi < 4; ++mi) {
    #pragma unroll
    for (int r = 0; r < 4; ++r) {
      const int row = bm * 128 + wr * 64 + mi * 16 + lk * 4 + r;  // C/D: row=(lane>>4)*4+reg
      float* cp = C + (size_t)row * HIDDIM + bn * 128 + wc * 64 + lrow;  // col=lane&15
      #pragma unroll
      for (int ni = 0; ni < 4; ++ni) {
        const float v = acc[mi][ni][r] + b1v[ni];
        cp[ni * 16] = v > 0.0f ? v : 0.0f;
      }
    }
  }
}

// ---------------------------------------------------------------------------
// Kernel 4: lin2 (2 dots of 2048) + softmax; one wave per graph
// ---------------------------------------------------------------------------
__global__ __launch_bounds__(256) void lin2_kernel(const float* __restrict__ h1,
                                                   const float* __restrict__ W2,
                                                   const float* __restrict__ b2,
                                                   float* __restrict__ out) {
  const int gid = blockIdx.x * 4 + (threadIdx.x >> 6);
  const int lane = threadIdx.x & 63;
  const float4* hp = (const float4*)(h1 + (size_t)gid * HIDDIM);
  const float4* w0 = (const float4*)W2;
  const float4* w1 = (const float4*)(W2 + HIDDIM);
  float s0 = 0.0f, s1 = 0.0f;
  #pragma unroll
  for (int i = 0; i < 8; ++i) {
    const float4 h = hp[i * 64 + lane];
    const float4 a = w0[i * 64 + lane];
    const float4 b = w1[i * 64 + lane];
    s0 += h.x * a.x + h.y * a.y + h.z * a.z + h.w * a.w;
    s1 += h.x * b.x + h.y * b.y + h.z * b.z + h.w * b.w;
  }
  #pragma unroll
  for (int off = 32; off > 0; off >>= 1) {
    s0 += __shfl_down(s0, off);
    s1 += __shfl_down(s1, off);
  }
  if (lane == 0) {
    const float l0 = s0 + b2[0];
    const float l1 = s1 + b2[1];
    const float mx = fmaxf(l0, l1);
    const float e0 = expf(l0 - mx);
    const float e1 = expf(l1 - mx);
    const float inv = 1.0f / (e0 + e1);
    out[(size_t)gid * 2]     = e0 * inv;
    out[(size_t)gid * 2 + 1] = e1 * inv;
  }
}

// ---------------------------------------------------------------------------
extern "C" void kernel_launch(void* const* d_in, const int* in_sizes, int n_in,
                              void* d_out, int out_size, void* d_ws, size_t ws_size,
                              hipStream_t stream) {
  const float* x  = (const float*)d_in[0];
  const float* Wc = (const float*)d_in[1];
  const float* bc = (const float*)d_in[2];
  const float* W1 = (const float*)d_in[3];
  const float* b1 = (const float*)d_in[4];
  const float* W2 = (const float*)d_in[5];
  const float* b2 = (const float*)d_in[6];
  const int* ei   = (const int*)d_in[7];
  // d_in[8] = batch (unused; graphs are contiguous 32-node blocks)

  // workspace layout (all fully rewritten every call; no cross-call state):
  //   [0, 64MB)        Abf  : bf16 A matrix [16384][2048]
  //   [64MB, 72MB)     W1bf : bf16 W1 [2048][2048]
  //   [72MB, 200MB)    h1   : fp32 lin1 output [16384][2048]
  unsigned short* Abf  = (unsigned short*)d_ws;
  unsigned short* W1bf = (unsigned short*)((char*)d_ws + (size_t)67108864);
  float*          h1   = (float*)((char*)d_ws + (size_t)75497472);

  cvt_w1<<<dim3(2048), dim3(256), 0, stream>>>(W1, W1bf);
  gcn_kernel<<<dim3(NGRAPH), dim3(256), 0, stream>>>(x, Wc, bc, ei, Abf);
  lin1_kernel<<<dim3(2048), dim3(256), 0, stream>>>(Abf, W1bf, b1, h1);
  lin2_kernel<<<dim3(4096), dim3(256), 0, stream>>>(h1, W2, b2, (float*)d_out);
}

// Round 2
// 298.358 us; speedup vs baseline: 1.2619x; 1.2619x over previous
//
#include <hip/hip_runtime.h>

#define NGRAPH 16384
#define NNODE  32
#define EMB    64
#define HIDDIM 2048
#define NTOT   (NGRAPH * NNODE)
#define ETOT   4194304      // NTOT * 8
#define EPG    256          // edges per graph (contiguous block per graph)

typedef __attribute__((ext_vector_type(8))) short bf16x8_t;
typedef __attribute__((ext_vector_type(8))) unsigned short u16x8_t;
typedef __attribute__((ext_vector_type(4))) float f32x4_t;

__device__ __forceinline__ unsigned short f2bf(float v) {
  // round-to-nearest-even f32 -> bf16 bits
  unsigned int u = __float_as_uint(v);
  u += 0x7fffu + ((u >> 16) & 1u);
  return (unsigned short)(u >> 16);
}

// ---------------------------------------------------------------------------
// Kernel 1: W1 (fp32 [2048][2048], row-major [out][in]) -> bf16
// ---------------------------------------------------------------------------
__global__ __launch_bounds__(256) void cvt_w1(const float* __restrict__ W,
                                              unsigned short* __restrict__ Wb) {
  const int i = blockIdx.x * 256 + threadIdx.x;   // 0..524287, 8 floats each
  const float4* p = (const float4*)W;
  const float4 a = p[2 * i];
  const float4 b = p[2 * i + 1];
  u16x8_t o;
  o[0] = f2bf(a.x); o[1] = f2bf(a.y); o[2] = f2bf(a.z); o[3] = f2bf(a.w);
  o[4] = f2bf(b.x); o[5] = f2bf(b.y); o[6] = f2bf(b.z); o[7] = f2bf(b.w);
  *((u16x8_t*)Wb + i) = o;
}

// ---------------------------------------------------------------------------
// Kernel 2: fused GCNConv + ReLU via MFMA, one block per graph.
// Reorder: out = relu( (adj @ x) @ Wc^T + bc )   (associativity)
//   agg:       xa = adj(32x32) @ x(32x64)      -> 8 mfma_16x16x32 (K=32)
//   transform: A  = xa(32x64) @ WcT(64x64)     -> 16 mfma (K=64, 2 steps)
// adj built in fp32 via LDS atomics, cvt to bf16. All LDS rows 16B-aligned,
// strides picked for <=2-way bank aliasing (free).
// ---------------------------------------------------------------------------
__global__ __launch_bounds__(256) void gcn_kernel(const float* __restrict__ x,
                                                  const float* __restrict__ Wc,
                                                  const float* __restrict__ bc,
                                                  const int* __restrict__ ei,
                                                  unsigned short* __restrict__ abf) {
  // phase-unioned buffer: early = xs fp32 [32][68] (8704 B)
  //                       late  = xas bf16 [32][72] (4608 B) + adjb bf16 [32][40] (2560 B)
  __shared__ __align__(16) char buf0[8704];
  __shared__ __align__(16) unsigned short xT[64 * 40];   // [feat][src] bf16; reused as out_s [32][72]
  __shared__ __align__(16) float adjm[NNODE][33];        // fp32 adjacency (atomics)
  __shared__ __align__(16) unsigned short Wcb[64 * 72];  // [outf][inf] bf16
  __shared__ float degs[NNODE];
  __shared__ float dinv[NNODE];
  __shared__ float bcs[EMB];

  float (*xs)[68]      = (float(*)[68])buf0;
  unsigned short* xas  = (unsigned short*)buf0;          // [32][72]
  unsigned short* adjb = (unsigned short*)(buf0 + 4608); // [32][40]

  const int g = blockIdx.x;
  const int t = threadIdx.x;

  // ---- phase A: stage x (coalesced fp32), Wc -> bf16 LDS, init adj/deg/bias
  {
    const int n = t >> 3, c0 = (t & 7) * 8;
    const float* xp = x + (size_t)g * (NNODE * EMB) + n * EMB + c0;
    *(float4*)&xs[n][c0]     = *(const float4*)xp;
    *(float4*)&xs[n][c0 + 4] = *(const float4*)(xp + 4);
  }
  for (int i = t; i < 512; i += 256) {
    const int r = i >> 3, c = (i & 7) * 8;
    const float4 a = *(const float4*)(Wc + r * EMB + c);
    const float4 b = *(const float4*)(Wc + r * EMB + c + 4);
    u16x8_t o;
    o[0] = f2bf(a.x); o[1] = f2bf(a.y); o[2] = f2bf(a.z); o[3] = f2bf(a.w);
    o[4] = f2bf(b.x); o[5] = f2bf(b.y); o[6] = f2bf(b.z); o[7] = f2bf(b.w);
    *(u16x8_t*)&Wcb[r * 72 + c] = o;
  }
  for (int i = t; i < NNODE * 33; i += 256) (&adjm[0][0])[i] = 0.0f;
  if (t < NNODE) degs[t] = 1.0f;              // self-loop
  if (t < EMB) bcs[t] = bc[t];
  const int sl = ei[(size_t)g * EPG + t] - g * NNODE;                 // src local
  const int dl = ei[(size_t)ETOT + (size_t)g * EPG + t] - g * NNODE;  // dst local
  __syncthreads();

  // ---- phase B: degree atomics + LDS transpose xs -> xT bf16 [feat][src]
  atomicAdd(&degs[dl], 1.0f);
  {
    const int f = t >> 2, s0 = (t & 3) * 8;
    u16x8_t o;
    #pragma unroll
    for (int j = 0; j < 8; ++j) o[j] = f2bf(xs[s0 + j][f]);
    *(u16x8_t*)&xT[f * 40 + s0] = o;
  }
  __syncthreads();
  if (t < NNODE) dinv[t] = rsqrtf(degs[t]);
  __syncthreads();
  atomicAdd(&adjm[dl][sl], dinv[sl] * dinv[dl]);
  if (t < NNODE) atomicAdd(&adjm[t][t], dinv[t] * dinv[t]);
  __syncthreads();
  for (int i = t; i < NNODE * NNODE; i += 256)
    adjb[(i >> 5) * 40 + (i & 31)] = f2bf(adjm[i >> 5][i & 31]);
  __syncthreads();

  // ---- phase C: agg MFMA  xa = adj @ x   (M=32,N=64,K=32; 2 tiles/wave)
  const int lane = t & 63, w = t >> 6;
  const int mt = w & 1, nt0 = (w >> 1) * 2;   // wave -> (M-tile, N-tile pair)
  const int lr = lane & 15, lk = lane >> 4;
  f32x4_t acc1[2];
  {
    const bf16x8_t af = *(const bf16x8_t*)&adjb[(mt * 16 + lr) * 40 + lk * 8];
    #pragma unroll
    for (int j = 0; j < 2; ++j) {
      const bf16x8_t bfr = *(const bf16x8_t*)&xT[((nt0 + j) * 16 + lr) * 40 + lk * 8];
      acc1[j] = __builtin_amdgcn_mfma_f32_16x16x32_bf16(af, bfr,
                  (f32x4_t){0.f, 0.f, 0.f, 0.f}, 0, 0, 0);
    }
  }
  // scatter xa -> LDS [node][feat] bf16 (A-operand layout for transform)
  #pragma unroll
  for (int j = 0; j < 2; ++j)
    #pragma unroll
    for (int r = 0; r < 4; ++r)
      xas[(mt * 16 + lk * 4 + r) * 72 + (nt0 + j) * 16 + lr] = f2bf(acc1[j][r]);
  __syncthreads();

  // ---- phase D: transform MFMA  A = relu(xa @ Wc^T + bc)  (K=64, 2 steps)
  f32x4_t acc2[2];
  acc2[0] = (f32x4_t){0.f, 0.f, 0.f, 0.f};
  acc2[1] = (f32x4_t){0.f, 0.f, 0.f, 0.f};
  #pragma unroll
  for (int k0 = 0; k0 < EMB; k0 += 32) {
    const bf16x8_t af = *(const bf16x8_t*)&xas[(mt * 16 + lr) * 72 + k0 + lk * 8];
    #pragma unroll
    for (int j = 0; j < 2; ++j) {
      const bf16x8_t bfr = *(const bf16x8_t*)&Wcb[((nt0 + j) * 16 + lr) * 72 + k0 + lk * 8];
      acc2[j] = __builtin_amdgcn_mfma_f32_16x16x32_bf16(af, bfr, acc2[j], 0, 0, 0);
    }
  }
  // epilogue: bias + relu -> bf16 -> LDS repack (reuse xT region) -> coalesced store
  unsigned short* outs = xT;   // [32][72]
  #pragma unroll
  for (int j = 0; j < 2; ++j)
    #pragma unroll
    for (int r = 0; r < 4; ++r) {
      const float v = acc2[j][r] + bcs[(nt0 + j) * 16 + lr];
      outs[(mt * 16 + lk * 4 + r) * 72 + (nt0 + j) * 16 + lr] = f2bf(fmaxf(v, 0.0f));
    }
  __syncthreads();
  {
    const int n = t >> 3, f0 = (t & 7) * 8;
    const u16x8_t o = *(const u16x8_t*)&outs[n * 72 + f0];
    *(u16x8_t*)(abf + (size_t)g * HIDDIM + n * EMB + f0) = o;
  }
}

// ---------------------------------------------------------------------------
// Kernel 3: lin1 GEMM  C[16384,2048] = relu(A[16384,2048] @ W1^T + b1), fp32 out
// bf16 MFMA, m97 structure: 128x128 tile, BK=32, 4 waves, global_load_lds w=16
// ---------------------------------------------------------------------------
__global__ __launch_bounds__(256) void lin1_kernel(const unsigned short* __restrict__ A,
                                                   const unsigned short* __restrict__ Bw,
                                                   const float* __restrict__ b1,
                                                   float* __restrict__ C) {
  __shared__ __align__(16) unsigned short As[128 * 32];  // [m][k] linear, 8KB
  __shared__ __align__(16) unsigned short Bs[128 * 32];

  // XCD swizzle (2048 % 8 == 0) + supertile: chunks of 8 bm x 16 bn (~12MB ws)
  const int bid = blockIdx.x;
  const int u = (bid & 7) * 256 + (bid >> 3);
  const int chunk = u >> 7;
  const int local = u & 127;
  const int bm = chunk * 8 + (local & 7);   // 0..127
  const int bn = local >> 3;                // 0..15

  const int t = threadIdx.x;
  const int lane = t & 63;
  const int w = t >> 6;
  const int wr = w >> 1, wc = w & 1;        // wave -> 64x64 quadrant
  const int lrow = lane & 15, lk = lane >> 4;

  // staging: 512 chunks of 16B per tile; chunk c -> row c>>2, k-col (c&3)*8
  const int c0 = w * 128 + lane;
  const int c1 = c0 + 64;
  const unsigned short* gA0 = A  + (size_t)(bm * 128 + (c0 >> 2)) * HIDDIM + (c0 & 3) * 8;
  const unsigned short* gA1 = A  + (size_t)(bm * 128 + (c1 >> 2)) * HIDDIM + (c1 & 3) * 8;
  const unsigned short* gB0 = Bw + (size_t)(bn * 128 + (c0 >> 2)) * HIDDIM + (c0 & 3) * 8;
  const unsigned short* gB1 = Bw + (size_t)(bn * 128 + (c1 >> 2)) * HIDDIM + (c1 & 3) * 8;
  unsigned short* lA0 = As + c0 * 8;
  unsigned short* lA1 = As + c1 * 8;
  unsigned short* lB0 = Bs + c0 * 8;
  unsigned short* lB1 = Bs + c1 * 8;

  f32x4_t acc[4][4];
  #pragma unroll
  for (int i = 0; i < 4; ++i)
    #pragma unroll
    for (int j = 0; j < 4; ++j) acc[i][j] = (f32x4_t){0.f, 0.f, 0.f, 0.f};

  for (int kt = 0; kt < HIDDIM; kt += 32) {
    __builtin_amdgcn_global_load_lds((const __attribute__((address_space(1))) void*)(gA0 + kt),
                                     (__attribute__((address_space(3))) void*)lA0, 16, 0, 0);
    __builtin_amdgcn_global_load_lds((const __attribute__((address_space(1))) void*)(gA1 + kt),
                                     (__attribute__((address_space(3))) void*)lA1, 16, 0, 0);
    __builtin_amdgcn_global_load_lds((const __attribute__((address_space(1))) void*)(gB0 + kt),
                                     (__attribute__((address_space(3))) void*)lB0, 16, 0, 0);
    __builtin_amdgcn_global_load_lds((const __attribute__((address_space(1))) void*)(gB1 + kt),
                                     (__attribute__((address_space(3))) void*)lB1, 16, 0, 0);
    __syncthreads();   // compiler emits vmcnt(0) drain + barrier

    bf16x8_t av[4], bv[4];
    #pragma unroll
    for (int mi = 0; mi < 4; ++mi)
      av[mi] = *(const bf16x8_t*)(As + (wr * 64 + mi * 16 + lrow) * 32 + lk * 8);
    #pragma unroll
    for (int ni = 0; ni < 4; ++ni)
      bv[ni] = *(const bf16x8_t*)(Bs + (wc * 64 + ni * 16 + lrow) * 32 + lk * 8);

    #pragma unroll
    for (int mi = 0; mi < 4; ++mi)
      #pragma unroll
      for (int ni = 0; ni < 4; ++ni)
        acc[mi][ni] = __builtin_amdgcn_mfma_f32_16x16x32_bf16(av[mi], bv[ni], acc[mi][ni], 0, 0, 0);
    __syncthreads();
  }

  // epilogue: + b1, relu, store fp32
  float b1v[4];
  #pragma unroll
  for (int ni = 0; ni < 4; ++ni) b1v[ni] = b1[bn * 128 + wc * 64 + ni * 16 + lrow];

  #pragma unroll
  for (int mi = 0; mi < 4; ++mi) {
    #pragma unroll
    for (int r = 0; r < 4; ++r) {
      const int row = bm * 128 + wr * 64 + mi * 16 + lk * 4 + r;  // C/D: row=(lane>>4)*4+reg
      float* cp = C + (size_t)row * HIDDIM + bn * 128 + wc * 64 + lrow;  // col=lane&15
      #pragma unroll
      for (int ni = 0; ni < 4; ++ni) {
        const float v = acc[mi][ni][r] + b1v[ni];
        cp[ni * 16] = v > 0.0f ? v : 0.0f;
      }
    }
  }
}

// ---------------------------------------------------------------------------
// Kernel 4: lin2 (2 dots of 2048) + softmax; one wave per graph
// ---------------------------------------------------------------------------
__global__ __launch_bounds__(256) void lin2_kernel(const float* __restrict__ h1,
                                                   const float* __restrict__ W2,
                                                   const float* __restrict__ b2,
                                                   float* __restrict__ out) {
  const int gid = blockIdx.x * 4 + (threadIdx.x >> 6);
  const int lane = threadIdx.x & 63;
  const float4* hp = (const float4*)(h1 + (size_t)gid * HIDDIM);
  const float4* w0 = (const float4*)W2;
  const float4* w1 = (const float4*)(W2 + HIDDIM);
  float s0 = 0.0f, s1 = 0.0f;
  #pragma unroll
  for (int i = 0; i < 8; ++i) {
    const float4 h = hp[i * 64 + lane];
    const float4 a = w0[i * 64 + lane];
    const float4 b = w1[i * 64 + lane];
    s0 += h.x * a.x + h.y * a.y + h.z * a.z + h.w * a.w;
    s1 += h.x * b.x + h.y * b.y + h.z * b.z + h.w * b.w;
  }
  #pragma unroll
  for (int off = 32; off > 0; off >>= 1) {
    s0 += __shfl_down(s0, off);
    s1 += __shfl_down(s1, off);
  }
  if (lane == 0) {
    const float l0 = s0 + b2[0];
    const float l1 = s1 + b2[1];
    const float mx = fmaxf(l0, l1);
    const float e0 = expf(l0 - mx);
    const float e1 = expf(l1 - mx);
    const float inv = 1.0f / (e0 + e1);
    out[(size_t)gid * 2]     = e0 * inv;
    out[(size_t)gid * 2 + 1] = e1 * inv;
  }
}

// ---------------------------------------------------------------------------
extern "C" void kernel_launch(void* const* d_in, const int* in_sizes, int n_in,
                              void* d_out, int out_size, void* d_ws, size_t ws_size,
                              hipStream_t stream) {
  const float* x  = (const float*)d_in[0];
  const float* Wc = (const float*)d_in[1];
  const float* bc = (const float*)d_in[2];
  const float* W1 = (const float*)d_in[3];
  const float* b1 = (const float*)d_in[4];
  const float* W2 = (const float*)d_in[5];
  const float* b2 = (const float*)d_in[6];
  const int* ei   = (const int*)d_in[7];
  // d_in[8] = batch (unused; graphs are contiguous 32-node blocks)

  // workspace layout (all fully rewritten every call; no cross-call state):
  //   [0, 64MB)        Abf  : bf16 A matrix [16384][2048]
  //   [64MB, 72MB)     W1bf : bf16 W1 [2048][2048]
  //   [72MB, 200MB)    h1   : fp32 lin1 output [16384][2048]
  unsigned short* Abf  = (unsigned short*)d_ws;
  unsigned short* W1bf = (unsigned short*)((char*)d_ws + (size_t)67108864);
  float*          h1   = (float*)((char*)d_ws + (size_t)75497472);

  cvt_w1<<<dim3(2048), dim3(256), 0, stream>>>(W1, W1bf);
  gcn_kernel<<<dim3(NGRAPH), dim3(256), 0, stream>>>(x, Wc, bc, ei, Abf);
  lin1_kernel<<<dim3(2048), dim3(256), 0, stream>>>(Abf, W1bf, b1, h1);
  lin2_kernel<<<dim3(4096), dim3(256), 0, stream>>>(h1, W2, b2, (float*)d_out);
}

// Round 3
// 270.810 us; speedup vs baseline: 1.3902x; 1.1017x over previous
//
#include <hip/hip_runtime.h>

#define NGRAPH 16384
#define NNODE  32
#define EMB    64
#define HIDDIM 2048
#define ETOT   4194304      // NTOT * 8
#define EPG    256          // edges per graph (contiguous block per graph)

typedef __attribute__((ext_vector_type(8))) short bf16x8_t;
typedef __attribute__((ext_vector_type(8))) unsigned short u16x8_t;
typedef __attribute__((ext_vector_type(4))) float f32x4_t;

__device__ __forceinline__ unsigned short f2bf(float v) {
  unsigned int u = __float_as_uint(v);
  u += 0x7fffu + ((u >> 16) & 1u);
  return (unsigned short)(u >> 16);
}

#define GLDS(SRC, DST)                                                          \
  __builtin_amdgcn_global_load_lds(                                             \
      (const __attribute__((address_space(1))) void*)(SRC),                     \
      (__attribute__((address_space(3))) void*)(DST), 16, 0, 0)

// ---------------------------------------------------------------------------
// Kernel 1: W1 fp32 -> bf16
// ---------------------------------------------------------------------------
__global__ __launch_bounds__(256) void cvt_w1(const float* __restrict__ W,
                                              unsigned short* __restrict__ Wb) {
  const int i = blockIdx.x * 256 + threadIdx.x;
  const float4* p = (const float4*)W;
  const float4 a = p[2 * i];
  const float4 b = p[2 * i + 1];
  u16x8_t o;
  o[0] = f2bf(a.x); o[1] = f2bf(a.y); o[2] = f2bf(a.z); o[3] = f2bf(a.w);
  o[4] = f2bf(b.x); o[5] = f2bf(b.y); o[6] = f2bf(b.z); o[7] = f2bf(b.w);
  *((u16x8_t*)Wb + i) = o;
}

// ---------------------------------------------------------------------------
// Kernel 2: fused GCNConv + ReLU via MFMA (unchanged from round 2)
// ---------------------------------------------------------------------------
__global__ __launch_bounds__(256) void gcn_kernel(const float* __restrict__ x,
                                                  const float* __restrict__ Wc,
                                                  const float* __restrict__ bc,
                                                  const int* __restrict__ ei,
                                                  unsigned short* __restrict__ abf) {
  __shared__ __align__(16) char buf0[8704];
  __shared__ __align__(16) unsigned short xT[64 * 40];
  __shared__ __align__(16) float adjm[NNODE][33];
  __shared__ __align__(16) unsigned short Wcb[64 * 72];
  __shared__ float degs[NNODE];
  __shared__ float dinv[NNODE];
  __shared__ float bcs[EMB];

  float (*xs)[68]      = (float(*)[68])buf0;
  unsigned short* xas  = (unsigned short*)buf0;          // [32][72]
  unsigned short* adjb = (unsigned short*)(buf0 + 4608); // [32][40]

  const int g = blockIdx.x;
  const int t = threadIdx.x;

  {
    const int n = t >> 3, c0 = (t & 7) * 8;
    const float* xp = x + (size_t)g * (NNODE * EMB) + n * EMB + c0;
    *(float4*)&xs[n][c0]     = *(const float4*)xp;
    *(float4*)&xs[n][c0 + 4] = *(const float4*)(xp + 4);
  }
  for (int i = t; i < 512; i += 256) {
    const int r = i >> 3, c = (i & 7) * 8;
    const float4 a = *(const float4*)(Wc + r * EMB + c);
    const float4 b = *(const float4*)(Wc + r * EMB + c + 4);
    u16x8_t o;
    o[0] = f2bf(a.x); o[1] = f2bf(a.y); o[2] = f2bf(a.z); o[3] = f2bf(a.w);
    o[4] = f2bf(b.x); o[5] = f2bf(b.y); o[6] = f2bf(b.z); o[7] = f2bf(b.w);
    *(u16x8_t*)&Wcb[r * 72 + c] = o;
  }
  for (int i = t; i < NNODE * 33; i += 256) (&adjm[0][0])[i] = 0.0f;
  if (t < NNODE) degs[t] = 1.0f;
  if (t < EMB) bcs[t] = bc[t];
  const int sl = ei[(size_t)g * EPG + t] - g * NNODE;
  const int dl = ei[(size_t)ETOT + (size_t)g * EPG + t] - g * NNODE;
  __syncthreads();

  atomicAdd(&degs[dl], 1.0f);
  {
    const int f = t >> 2, s0 = (t & 3) * 8;
    u16x8_t o;
    #pragma unroll
    for (int j = 0; j < 8; ++j) o[j] = f2bf(xs[s0 + j][f]);
    *(u16x8_t*)&xT[f * 40 + s0] = o;
  }
  __syncthreads();
  if (t < NNODE) dinv[t] = rsqrtf(degs[t]);
  __syncthreads();
  atomicAdd(&adjm[dl][sl], dinv[sl] * dinv[dl]);
  if (t < NNODE) atomicAdd(&adjm[t][t], dinv[t] * dinv[t]);
  __syncthreads();
  for (int i = t; i < NNODE * NNODE; i += 256)
    adjb[(i >> 5) * 40 + (i & 31)] = f2bf(adjm[i >> 5][i & 31]);
  __syncthreads();

  const int lane = t & 63, w = t >> 6;
  const int mt = w & 1, nt0 = (w >> 1) * 2;
  const int lr = lane & 15, lk = lane >> 4;
  f32x4_t acc1[2];
  {
    const bf16x8_t af = *(const bf16x8_t*)&adjb[(mt * 16 + lr) * 40 + lk * 8];
    #pragma unroll
    for (int j = 0; j < 2; ++j) {
      const bf16x8_t bfr = *(const bf16x8_t*)&xT[((nt0 + j) * 16 + lr) * 40 + lk * 8];
      acc1[j] = __builtin_amdgcn_mfma_f32_16x16x32_bf16(af, bfr,
                  (f32x4_t){0.f, 0.f, 0.f, 0.f}, 0, 0, 0);
    }
  }
  #pragma unroll
  for (int j = 0; j < 2; ++j)
    #pragma unroll
    for (int r = 0; r < 4; ++r)
      xas[(mt * 16 + lk * 4 + r) * 72 + (nt0 + j) * 16 + lr] = f2bf(acc1[j][r]);
  __syncthreads();

  f32x4_t acc2[2];
  acc2[0] = (f32x4_t){0.f, 0.f, 0.f, 0.f};
  acc2[1] = (f32x4_t){0.f, 0.f, 0.f, 0.f};
  #pragma unroll
  for (int k0 = 0; k0 < EMB; k0 += 32) {
    const bf16x8_t af = *(const bf16x8_t*)&xas[(mt * 16 + lr) * 72 + k0 + lk * 8];
    #pragma unroll
    for (int j = 0; j < 2; ++j) {
      const bf16x8_t bfr = *(const bf16x8_t*)&Wcb[((nt0 + j) * 16 + lr) * 72 + k0 + lk * 8];
      acc2[j] = __builtin_amdgcn_mfma_f32_16x16x32_bf16(af, bfr, acc2[j], 0, 0, 0);
    }
  }
  unsigned short* outs = xT;
  #pragma unroll
  for (int j = 0; j < 2; ++j)
    #pragma unroll
    for (int r = 0; r < 4; ++r) {
      const float v = acc2[j][r] + bcs[(nt0 + j) * 16 + lr];
      outs[(mt * 16 + lk * 4 + r) * 72 + (nt0 + j) * 16 + lr] = f2bf(fmaxf(v, 0.0f));
    }
  __syncthreads();
  {
    const int n = t >> 3, f0 = (t & 7) * 8;
    const u16x8_t o = *(const u16x8_t*)&outs[n * 72 + f0];
    *(u16x8_t*)(abf + (size_t)g * HIDDIM + n * EMB + f0) = o;
  }
}

// ---------------------------------------------------------------------------
// Kernel 3: lin1 GEMM  C = relu(A @ W1^T + b1)
// 256x256 tile, BK=64, 512 thr (8 waves 4Mx2N), T2 XOR-swizzle,
// part-granular double-buffer pipeline with counted vmcnt(4) (T3/T4),
// raw s_barrier (2/tile) + setprio (T5).
// ---------------------------------------------------------------------------
__global__ __launch_bounds__(512, 1) void lin1_kernel(const unsigned short* __restrict__ A,
                                                      const unsigned short* __restrict__ Bw,
                                                      const float* __restrict__ b1,
                                                      float* __restrict__ C) {
  __shared__ __align__(16) unsigned short sA[2][256 * 64];  // 2 x 32KB
  __shared__ __align__(16) unsigned short sB[2][256 * 64];  // 2 x 32KB

  // XCD swizzle: 512 blocks = 64 bm x 8 bn; XCD x -> bm chunk [8x, 8x+8), all bn
  const int bid = blockIdx.x;
  const int u = (bid & 7) * 64 + (bid >> 3);
  const int bm = u >> 3, bn = u & 7;

  const int tid = threadIdx.x;
  const int lane = tid & 63, w = tid >> 6;
  const int wm = w >> 1, wn = w & 1;       // 4 M-waves x 2 N-waves
  const int lr = lane & 15, lk = lane >> 4;

  // ---- staging geometry: part = 128 rows x 64 k = 16KB = 1024 x 16B chunks
  // thread handles chunks {tid, tid+512}; LDS dest linear; global k pre-swizzled
  const int r0 = tid >> 3;                                    // row of chunk tid
  const int kge = ((((tid & 7) * 16) ^ ((r0 & 7) << 4)) >> 1);  // elem offset in row
  const unsigned short* gA = A  + (size_t)(bm * 256 + r0) * HIDDIM + kge;
  const unsigned short* gB = Bw + (size_t)(bn * 256 + r0) * HIDDIM + kge;
  const int ldsOff0 = tid * 8;                                // ushort units

  auto stage = [&](const unsigned short* gbase, unsigned short* lbase, int tile, int part) {
    const unsigned short* s = gbase + (size_t)part * 128 * HIDDIM + tile * 64;
    unsigned short* l = lbase + part * 8192 + ldsOff0;
    GLDS(s, l);
    GLDS(s + (size_t)64 * HIDDIM, l + 4096);
  };

  // ---- fragment-read offsets (swizzled)
  int aoff[4];
  #pragma unroll
  for (int mi = 0; mi < 4; ++mi)
    aoff[mi] = (wm >> 1) * 8192 + ((wm * 64 + mi * 16 + lr) & 127) * 64;
  const int koff0 = (((lk * 16)      ^ ((lr & 7) << 4)) >> 1);
  const int koff1 = (((64 + lk * 16) ^ ((lr & 7) << 4)) >> 1);
  const int bbase = wn * 8192 + lr * 64;

  f32x4_t acc[4][8];
  #pragma unroll
  for (int i = 0; i < 4; ++i)
    #pragma unroll
    for (int j = 0; j < 8; ++j) acc[i][j] = (f32x4_t){0.f, 0.f, 0.f, 0.f};

  // ---- prologue: A(0), B(0), A(1)   (12 loads; newest 4 = A(1))
  stage(gA, sA[0], 0, 0); stage(gA, sA[0], 0, 1);
  stage(gB, sB[0], 0, 0); stage(gB, sB[0], 0, 1);
  stage(gA, sA[1], 1, 0); stage(gA, sA[1], 1, 1);

  for (int t = 0; t < 32; ++t) {
    // tile-start sync: allow the 2 newest stage-ops (A(t+1), 4 loads) in flight
    if (t < 31) { asm volatile("s_waitcnt vmcnt(4)" ::: "memory"); }
    else        { asm volatile("s_waitcnt vmcnt(0)" ::: "memory"); }
    asm volatile("s_waitcnt lgkmcnt(0)" ::: "memory");
    __builtin_amdgcn_sched_barrier(0);
    __builtin_amdgcn_s_barrier();

    unsigned short* cA = sA[t & 1];
    unsigned short* cB = sB[t & 1];
    unsigned short* nB = sB[(t + 1) & 1];

    // ---- phase 0: read ALL A-frags + B-frags 0,1; stage B(t+1) part 0
    bf16x8_t af[4][2], bv[2][2];
    #pragma unroll
    for (int mi = 0; mi < 4; ++mi) {
      af[mi][0] = *(const bf16x8_t*)&cA[aoff[mi] + koff0];
      af[mi][1] = *(const bf16x8_t*)&cA[aoff[mi] + koff1];
    }
    #pragma unroll
    for (int j = 0; j < 2; ++j) {
      bv[j][0] = *(const bf16x8_t*)&cB[bbase + j * 1024 + koff0];
      bv[j][1] = *(const bf16x8_t*)&cB[bbase + j * 1024 + koff1];
    }
    if (t < 31) stage(gB, nB, t + 1, 0);
    __builtin_amdgcn_s_setprio(1);
    #pragma unroll
    for (int j = 0; j < 2; ++j)
      #pragma unroll
      for (int mi = 0; mi < 4; ++mi) {
        acc[mi][j] = __builtin_amdgcn_mfma_f32_16x16x32_bf16(af[mi][0], bv[j][0], acc[mi][j], 0, 0, 0);
        acc[mi][j] = __builtin_amdgcn_mfma_f32_16x16x32_bf16(af[mi][1], bv[j][1], acc[mi][j], 0, 0, 0);
      }
    __builtin_amdgcn_s_setprio(0);

    // mid barrier: all waves finished reading A region of current buffer
    asm volatile("s_waitcnt lgkmcnt(0)" ::: "memory");
    __builtin_amdgcn_sched_barrier(0);
    __builtin_amdgcn_s_barrier();

    // ---- phases 1..3: stream B-frags; stage B(t+1) p1, A(t+2) p0, A(t+2) p1
    #pragma unroll
    for (int ph = 1; ph < 4; ++ph) {
      #pragma unroll
      for (int j = 0; j < 2; ++j) {
        bv[j][0] = *(const bf16x8_t*)&cB[bbase + (ph * 2 + j) * 1024 + koff0];
        bv[j][1] = *(const bf16x8_t*)&cB[bbase + (ph * 2 + j) * 1024 + koff1];
      }
      if (ph == 1)      { if (t < 31) stage(gB, nB, t + 1, 1); }
      else if (ph == 2) { if (t < 30) stage(gA, cA, t + 2, 0); }
      else              { if (t < 30) stage(gA, cA, t + 2, 1); }
      __builtin_amdgcn_s_setprio(1);
      #pragma unroll
      for (int j = 0; j < 2; ++j)
        #pragma unroll
        for (int mi = 0; mi < 4; ++mi) {
          acc[mi][ph * 2 + j] = __builtin_amdgcn_mfma_f32_16x16x32_bf16(af[mi][0], bv[j][0], acc[mi][ph * 2 + j], 0, 0, 0);
          acc[mi][ph * 2 + j] = __builtin_amdgcn_mfma_f32_16x16x32_bf16(af[mi][1], bv[j][1], acc[mi][ph * 2 + j], 0, 0, 0);
        }
      __builtin_amdgcn_s_setprio(0);
    }
  }

  // ---- epilogue: + b1, relu, fp32 store
  const int crow0 = bm * 256 + wm * 64 + lk * 4;
  const int ccol0 = bn * 256 + wn * 128 + lr;
  float b1v[8];
  #pragma unroll
  for (int ni = 0; ni < 8; ++ni) b1v[ni] = b1[ccol0 + ni * 16];
  #pragma unroll
  for (int mi = 0; mi < 4; ++mi)
    #pragma unroll
    for (int r = 0; r < 4; ++r) {
      float* cp = C + (size_t)(crow0 + mi * 16 + r) * HIDDIM + ccol0;
      #pragma unroll
      for (int ni = 0; ni < 8; ++ni) {
        const float v = acc[mi][ni][r] + b1v[ni];
        cp[ni * 16] = v > 0.0f ? v : 0.0f;
      }
    }
}

// ---------------------------------------------------------------------------
// Kernel 4: lin2 + softmax (unchanged)
// ---------------------------------------------------------------------------
__global__ __launch_bounds__(256) void lin2_kernel(const float* __restrict__ h1,
                                                   const float* __restrict__ W2,
                                                   const float* __restrict__ b2,
                                                   float* __restrict__ out) {
  const int gid = blockIdx.x * 4 + (threadIdx.x >> 6);
  const int lane = threadIdx.x & 63;
  const float4* hp = (const float4*)(h1 + (size_t)gid * HIDDIM);
  const float4* w0 = (const float4*)W2;
  const float4* w1 = (const float4*)(W2 + HIDDIM);
  float s0 = 0.0f, s1 = 0.0f;
  #pragma unroll
  for (int i = 0; i < 8; ++i) {
    const float4 h = hp[i * 64 + lane];
    const float4 a = w0[i * 64 + lane];
    const float4 b = w1[i * 64 + lane];
    s0 += h.x * a.x + h.y * a.y + h.z * a.z + h.w * a.w;
    s1 += h.x * b.x + h.y * b.y + h.z * b.z + h.w * b.w;
  }
  #pragma unroll
  for (int off = 32; off > 0; off >>= 1) {
    s0 += __shfl_down(s0, off);
    s1 += __shfl_down(s1, off);
  }
  if (lane == 0) {
    const float l0 = s0 + b2[0];
    const float l1 = s1 + b2[1];
    const float mx = fmaxf(l0, l1);
    const float e0 = expf(l0 - mx);
    const float e1 = expf(l1 - mx);
    const float inv = 1.0f / (e0 + e1);
    out[(size_t)gid * 2]     = e0 * inv;
    out[(size_t)gid * 2 + 1] = e1 * inv;
  }
}

// ---------------------------------------------------------------------------
extern "C" void kernel_launch(void* const* d_in, const int* in_sizes, int n_in,
                              void* d_out, int out_size, void* d_ws, size_t ws_size,
                              hipStream_t stream) {
  const float* x  = (const float*)d_in[0];
  const float* Wc = (const float*)d_in[1];
  const float* bc = (const float*)d_in[2];
  const float* W1 = (const float*)d_in[3];
  const float* b1 = (const float*)d_in[4];
  const float* W2 = (const float*)d_in[5];
  const float* b2 = (const float*)d_in[6];
  const int* ei   = (const int*)d_in[7];

  unsigned short* Abf  = (unsigned short*)d_ws;
  unsigned short* W1bf = (unsigned short*)((char*)d_ws + (size_t)67108864);
  float*          h1   = (float*)((char*)d_ws + (size_t)75497472);

  cvt_w1<<<dim3(2048), dim3(256), 0, stream>>>(W1, W1bf);
  gcn_kernel<<<dim3(NGRAPH), dim3(256), 0, stream>>>(x, Wc, bc, ei, Abf);
  lin1_kernel<<<dim3(512), dim3(512), 0, stream>>>(Abf, W1bf, b1, h1);
  lin2_kernel<<<dim3(4096), dim3(256), 0, stream>>>(h1, W2, b2, (float*)d_out);
}

// Round 4
// 254.675 us; speedup vs baseline: 1.4783x; 1.0634x over previous
//
#include <hip/hip_runtime.h>

#define NGRAPH 16384
#define NNODE  32
#define EMB    64
#define HIDDIM 2048
#define ETOT   4194304      // NTOT * 8
#define EPG    256          // edges per graph (contiguous block per graph)

typedef __attribute__((ext_vector_type(8))) short bf16x8_t;
typedef __attribute__((ext_vector_type(8))) unsigned short u16x8_t;
typedef __attribute__((ext_vector_type(4))) float f32x4_t;

__device__ __forceinline__ unsigned short f2bf(float v) {
  unsigned int u = __float_as_uint(v);
  u += 0x7fffu + ((u >> 16) & 1u);
  return (unsigned short)(u >> 16);
}

#define GLDS(SRC, DST)                                                          \
  __builtin_amdgcn_global_load_lds(                                             \
      (const __attribute__((address_space(1))) void*)(SRC),                     \
      (__attribute__((address_space(3))) void*)(DST), 16, 0, 0)

// ---------------------------------------------------------------------------
// Kernel 1: W1 fp32 -> bf16
// ---------------------------------------------------------------------------
__global__ __launch_bounds__(256) void cvt_w1(const float* __restrict__ W,
                                              unsigned short* __restrict__ Wb) {
  const int i = blockIdx.x * 256 + threadIdx.x;
  const float4* p = (const float4*)W;
  const float4 a = p[2 * i];
  const float4 b = p[2 * i + 1];
  u16x8_t o;
  o[0] = f2bf(a.x); o[1] = f2bf(a.y); o[2] = f2bf(a.z); o[3] = f2bf(a.w);
  o[4] = f2bf(b.x); o[5] = f2bf(b.y); o[6] = f2bf(b.z); o[7] = f2bf(b.w);
  *((u16x8_t*)Wb + i) = o;
}

// ---------------------------------------------------------------------------
// Kernel 2: fused GCNConv + ReLU via MFMA (unchanged)
// ---------------------------------------------------------------------------
__global__ __launch_bounds__(256) void gcn_kernel(const float* __restrict__ x,
                                                  const float* __restrict__ Wc,
                                                  const float* __restrict__ bc,
                                                  const int* __restrict__ ei,
                                                  unsigned short* __restrict__ abf) {
  __shared__ __align__(16) char buf0[8704];
  __shared__ __align__(16) unsigned short xT[64 * 40];
  __shared__ __align__(16) float adjm[NNODE][33];
  __shared__ __align__(16) unsigned short Wcb[64 * 72];
  __shared__ float degs[NNODE];
  __shared__ float dinv[NNODE];
  __shared__ float bcs[EMB];

  float (*xs)[68]      = (float(*)[68])buf0;
  unsigned short* xas  = (unsigned short*)buf0;          // [32][72]
  unsigned short* adjb = (unsigned short*)(buf0 + 4608); // [32][40]

  const int g = blockIdx.x;
  const int t = threadIdx.x;

  {
    const int n = t >> 3, c0 = (t & 7) * 8;
    const float* xp = x + (size_t)g * (NNODE * EMB) + n * EMB + c0;
    *(float4*)&xs[n][c0]     = *(const float4*)xp;
    *(float4*)&xs[n][c0 + 4] = *(const float4*)(xp + 4);
  }
  for (int i = t; i < 512; i += 256) {
    const int r = i >> 3, c = (i & 7) * 8;
    const float4 a = *(const float4*)(Wc + r * EMB + c);
    const float4 b = *(const float4*)(Wc + r * EMB + c + 4);
    u16x8_t o;
    o[0] = f2bf(a.x); o[1] = f2bf(a.y); o[2] = f2bf(a.z); o[3] = f2bf(a.w);
    o[4] = f2bf(b.x); o[5] = f2bf(b.y); o[6] = f2bf(b.z); o[7] = f2bf(b.w);
    *(u16x8_t*)&Wcb[r * 72 + c] = o;
  }
  for (int i = t; i < NNODE * 33; i += 256) (&adjm[0][0])[i] = 0.0f;
  if (t < NNODE) degs[t] = 1.0f;
  if (t < EMB) bcs[t] = bc[t];
  const int sl = ei[(size_t)g * EPG + t] - g * NNODE;
  const int dl = ei[(size_t)ETOT + (size_t)g * EPG + t] - g * NNODE;
  __syncthreads();

  atomicAdd(&degs[dl], 1.0f);
  {
    const int f = t >> 2, s0 = (t & 3) * 8;
    u16x8_t o;
    #pragma unroll
    for (int j = 0; j < 8; ++j) o[j] = f2bf(xs[s0 + j][f]);
    *(u16x8_t*)&xT[f * 40 + s0] = o;
  }
  __syncthreads();
  if (t < NNODE) dinv[t] = rsqrtf(degs[t]);
  __syncthreads();
  atomicAdd(&adjm[dl][sl], dinv[sl] * dinv[dl]);
  if (t < NNODE) atomicAdd(&adjm[t][t], dinv[t] * dinv[t]);
  __syncthreads();
  for (int i = t; i < NNODE * NNODE; i += 256)
    adjb[(i >> 5) * 40 + (i & 31)] = f2bf(adjm[i >> 5][i & 31]);
  __syncthreads();

  const int lane = t & 63, w = t >> 6;
  const int mt = w & 1, nt0 = (w >> 1) * 2;
  const int lr = lane & 15, lk = lane >> 4;
  f32x4_t acc1[2];
  {
    const bf16x8_t af = *(const bf16x8_t*)&adjb[(mt * 16 + lr) * 40 + lk * 8];
    #pragma unroll
    for (int j = 0; j < 2; ++j) {
      const bf16x8_t bfr = *(const bf16x8_t*)&xT[((nt0 + j) * 16 + lr) * 40 + lk * 8];
      acc1[j] = __builtin_amdgcn_mfma_f32_16x16x32_bf16(af, bfr,
                  (f32x4_t){0.f, 0.f, 0.f, 0.f}, 0, 0, 0);
    }
  }
  #pragma unroll
  for (int j = 0; j < 2; ++j)
    #pragma unroll
    for (int r = 0; r < 4; ++r)
      xas[(mt * 16 + lk * 4 + r) * 72 + (nt0 + j) * 16 + lr] = f2bf(acc1[j][r]);
  __syncthreads();

  f32x4_t acc2[2];
  acc2[0] = (f32x4_t){0.f, 0.f, 0.f, 0.f};
  acc2[1] = (f32x4_t){0.f, 0.f, 0.f, 0.f};
  #pragma unroll
  for (int k0 = 0; k0 < EMB; k0 += 32) {
    const bf16x8_t af = *(const bf16x8_t*)&xas[(mt * 16 + lr) * 72 + k0 + lk * 8];
    #pragma unroll
    for (int j = 0; j < 2; ++j) {
      const bf16x8_t bfr = *(const bf16x8_t*)&Wcb[((nt0 + j) * 16 + lr) * 72 + k0 + lk * 8];
      acc2[j] = __builtin_amdgcn_mfma_f32_16x16x32_bf16(af, bfr, acc2[j], 0, 0, 0);
    }
  }
  unsigned short* outs = xT;
  #pragma unroll
  for (int j = 0; j < 2; ++j)
    #pragma unroll
    for (int r = 0; r < 4; ++r) {
      const float v = acc2[j][r] + bcs[(nt0 + j) * 16 + lr];
      outs[(mt * 16 + lk * 4 + r) * 72 + (nt0 + j) * 16 + lr] = f2bf(fmaxf(v, 0.0f));
    }
  __syncthreads();
  {
    const int n = t >> 3, f0 = (t & 7) * 8;
    const u16x8_t o = *(const u16x8_t*)&outs[n * 72 + f0];
    *(u16x8_t*)(abf + (size_t)g * HIDDIM + n * EMB + f0) = o;
  }
}

// ---------------------------------------------------------------------------
// Kernel 3: lin1 GEMM  C = relu(A @ W1^T + b1)  — m201-style 8-phase schedule
// BM=BN=256, BK=64, 512 thr (8 waves 2Mx4N, per-wave 128x64).
// LDS: dbuf[2] x {A,B} x half[2] x [128][64] bf16 = 128KB, T2 XOR-swizzled.
// Per phase: {ds-read quadrant subtile || stage 1 half-tile -> lgkm0 ->
// barrier -> setprio(1) 16xMFMA setprio(0)}. vmcnt(4) gates at p3/p7 only
// (vmcnt(0) last iter), always immediately before a barrier.
// ---------------------------------------------------------------------------
__global__ __launch_bounds__(512, 1) void lin1_kernel(const unsigned short* __restrict__ A,
                                                      const unsigned short* __restrict__ Bw,
                                                      const float* __restrict__ b1,
                                                      float* __restrict__ C) {
  __shared__ __align__(16) unsigned short sh[65536];   // 128 KB

  // XCD-pinned bn: each XCD owns one 256-col W-slice (1MB -> L2-resident)
  const int bid = blockIdx.x;
  const int bn = bid & 7, bm = bid >> 3;

  const int tid = threadIdx.x;
  const int lane = tid & 63, w = tid >> 6;
  const int wm = w >> 2, wn = w & 3;       // 2 M-waves x 4 N-waves
  const int lr = lane & 15, lk = lane >> 4;

  // staging: half-tile = 128 rows x 64 k; thread t -> rows (t>>3), (t>>3)+64
  const int r0 = tid >> 3;
  const int kge = ((((tid & 7) * 16) ^ ((r0 & 7) << 4)) >> 1);  // swizzled elem
  const unsigned short* gA = A  + (size_t)(bm * 256 + r0) * HIDDIM + kge;
  const unsigned short* gB = Bw + (size_t)(bn * 256 + r0) * HIDDIM + kge;

  auto stage = [&](const unsigned short* gb, int d, int mat, int half, int tile) {
    const unsigned short* s = gb + (size_t)(half * 128) * HIDDIM + tile * 64;
    unsigned short* l = &sh[d * 32768 + mat * 16384 + half * 8192 + tid * 8];
    GLDS(s, l);
    GLDS(s + (size_t)64 * HIDDIM, l + 4096);
  };

  // fragment-read bases (ushort units, relative to dbuf base)
  const int arow = wm * 8192 + lr * 64;                          // A: mat 0, half wm
  const int brow = 16384 + (wn >> 1) * 8192 + ((wn & 1) * 64 + lr) * 64;
  int eoff[2];
  eoff[0] = (lk * 8) ^ ((lr & 7) << 3);
  eoff[1] = (32 + lk * 8) ^ ((lr & 7) << 3);

  f32x4_t acc[8][4];
  #pragma unroll
  for (int i = 0; i < 8; ++i)
    #pragma unroll
    for (int j = 0; j < 4; ++j) acc[i][j] = (f32x4_t){0.f, 0.f, 0.f, 0.f};

  // ---- prologue: tile0 (A+B) -> dbuf0, tile1 B -> dbuf1; gate; barrier
  stage(gA, 0, 0, 0, 0); stage(gA, 0, 0, 1, 0);
  stage(gB, 0, 1, 0, 0); stage(gB, 0, 1, 1, 0);
  stage(gB, 1, 1, 0, 1); stage(gB, 1, 1, 1, 1);
  asm volatile("s_waitcnt vmcnt(4)" ::: "memory");
  __builtin_amdgcn_sched_barrier(0);
  __builtin_amdgcn_s_barrier();

  bf16x8_t af[4][2], bv0[2][2], bv1[2][2];

  for (int it = 0; it < 16; ++it) {
    const int o = 2 * it + 1;
    const bool more = (it < 15);

    #pragma unroll
    for (int half = 0; half < 2; ++half) {     // half 0: dbuf0 (tile 2it), 1: dbuf1
      const int dof = half * 32768;

      // ---- phase 0/4: read A0 quadrant + B0; stage A-half0
      #pragma unroll
      for (int mi = 0; mi < 4; ++mi) {
        af[mi][0] = *(const bf16x8_t*)&sh[dof + arow + mi * 1024 + eoff[0]];
        af[mi][1] = *(const bf16x8_t*)&sh[dof + arow + mi * 1024 + eoff[1]];
      }
      #pragma unroll
      for (int ni = 0; ni < 2; ++ni) {
        bv0[ni][0] = *(const bf16x8_t*)&sh[dof + brow + ni * 1024 + eoff[0]];
        bv0[ni][1] = *(const bf16x8_t*)&sh[dof + brow + ni * 1024 + eoff[1]];
      }
      if (half == 0) stage(gA, 1, 0, 0, o);
      else if (more) stage(gA, 0, 0, 0, o + 1);
      asm volatile("s_waitcnt lgkmcnt(0)" ::: "memory");
      __builtin_amdgcn_sched_barrier(0);
      __builtin_amdgcn_s_barrier();
      __builtin_amdgcn_s_setprio(1);
      #pragma unroll
      for (int kk = 0; kk < 2; ++kk)
        #pragma unroll
        for (int mi = 0; mi < 4; ++mi)
          #pragma unroll
          for (int ni = 0; ni < 2; ++ni)
            acc[mi][ni] = __builtin_amdgcn_mfma_f32_16x16x32_bf16(af[mi][kk], bv0[ni][kk], acc[mi][ni], 0, 0, 0);
      __builtin_amdgcn_s_setprio(0);

      // ---- phase 1/5: read B1; stage A-half1
      #pragma unroll
      for (int ni = 0; ni < 2; ++ni) {
        bv1[ni][0] = *(const bf16x8_t*)&sh[dof + brow + (ni + 2) * 1024 + eoff[0]];
        bv1[ni][1] = *(const bf16x8_t*)&sh[dof + brow + (ni + 2) * 1024 + eoff[1]];
      }
      if (half == 0) stage(gA, 1, 0, 1, o);
      else if (more) stage(gA, 0, 0, 1, o + 1);
      asm volatile("s_waitcnt lgkmcnt(0)" ::: "memory");
      __builtin_amdgcn_sched_barrier(0);
      __builtin_amdgcn_s_barrier();
      __builtin_amdgcn_s_setprio(1);
      #pragma unroll
      for (int kk = 0; kk < 2; ++kk)
        #pragma unroll
        for (int mi = 0; mi < 4; ++mi)
          #pragma unroll
          for (int ni = 0; ni < 2; ++ni)
            acc[mi][ni + 2] = __builtin_amdgcn_mfma_f32_16x16x32_bf16(af[mi][kk], bv1[ni][kk], acc[mi][ni + 2], 0, 0, 0);
      __builtin_amdgcn_s_setprio(0);

      // ---- phase 2/6: read A1 quadrant; stage B-half0 of tile+2
      #pragma unroll
      for (int mi = 0; mi < 4; ++mi) {
        af[mi][0] = *(const bf16x8_t*)&sh[dof + arow + (mi + 4) * 1024 + eoff[0]];
        af[mi][1] = *(const bf16x8_t*)&sh[dof + arow + (mi + 4) * 1024 + eoff[1]];
      }
      if (more) stage(gB, half, 1, 0, (half == 0) ? (o + 1) : (o + 2));
      asm volatile("s_waitcnt lgkmcnt(0)" ::: "memory");
      __builtin_amdgcn_sched_barrier(0);
      __builtin_amdgcn_s_barrier();
      __builtin_amdgcn_s_setprio(1);
      #pragma unroll
      for (int kk = 0; kk < 2; ++kk)
        #pragma unroll
        for (int mi = 0; mi < 4; ++mi)
          #pragma unroll
          for (int ni = 0; ni < 2; ++ni)
            acc[mi + 4][ni + 2] = __builtin_amdgcn_mfma_f32_16x16x32_bf16(af[mi][kk], bv1[ni][kk], acc[mi + 4][ni + 2], 0, 0, 0);
      __builtin_amdgcn_s_setprio(0);

      // ---- phase 3/7: no reads; stage B-half1 of tile+2; vmcnt gate + barrier
      if (more) stage(gB, half, 1, 1, (half == 0) ? (o + 1) : (o + 2));
      asm volatile("s_waitcnt lgkmcnt(0)" ::: "memory");
      if (more) { asm volatile("s_waitcnt vmcnt(4)" ::: "memory"); }
      else      { asm volatile("s_waitcnt vmcnt(0)" ::: "memory"); }
      __builtin_amdgcn_sched_barrier(0);
      __builtin_amdgcn_s_barrier();
      __builtin_amdgcn_s_setprio(1);
      #pragma unroll
      for (int kk = 0; kk < 2; ++kk)
        #pragma unroll
        for (int mi = 0; mi < 4; ++mi)
          #pragma unroll
          for (int ni = 0; ni < 2; ++ni)
            acc[mi + 4][ni] = __builtin_amdgcn_mfma_f32_16x16x32_bf16(af[mi][kk], bv0[ni][kk], acc[mi + 4][ni], 0, 0, 0);
      __builtin_amdgcn_s_setprio(0);
    }
  }

  // ---- epilogue: + b1, relu, fp32 store
  const int crow0 = bm * 256 + wm * 128 + lk * 4;
  const int ccol0 = bn * 256 + wn * 64 + lr;
  float b1v[4];
  #pragma unroll
  for (int ni = 0; ni < 4; ++ni) b1v[ni] = b1[ccol0 + ni * 16];
  #pragma unroll
  for (int mi = 0; mi < 8; ++mi)
    #pragma unroll
    for (int r = 0; r < 4; ++r) {
      float* cp = C + (size_t)(crow0 + mi * 16 + r) * HIDDIM + ccol0;
      #pragma unroll
      for (int ni = 0; ni < 4; ++ni) {
        const float v = acc[mi][ni][r] + b1v[ni];
        cp[ni * 16] = v > 0.0f ? v : 0.0f;
      }
    }
}

// ---------------------------------------------------------------------------
// Kernel 4: lin2 + softmax (unchanged)
// ---------------------------------------------------------------------------
__global__ __launch_bounds__(256) void lin2_kernel(const float* __restrict__ h1,
                                                   const float* __restrict__ W2,
                                                   const float* __restrict__ b2,
                                                   float* __restrict__ out) {
  const int gid = blockIdx.x * 4 + (threadIdx.x >> 6);
  const int lane = threadIdx.x & 63;
  const float4* hp = (const float4*)(h1 + (size_t)gid * HIDDIM);
  const float4* w0 = (const float4*)W2;
  const float4* w1 = (const float4*)(W2 + HIDDIM);
  float s0 = 0.0f, s1 = 0.0f;
  #pragma unroll
  for (int i = 0; i < 8; ++i) {
    const float4 h = hp[i * 64 + lane];
    const float4 a = w0[i * 64 + lane];
    const float4 b = w1[i * 64 + lane];
    s0 += h.x * a.x + h.y * a.y + h.z * a.z + h.w * a.w;
    s1 += h.x * b.x + h.y * b.y + h.z * b.z + h.w * b.w;
  }
  #pragma unroll
  for (int off = 32; off > 0; off >>= 1) {
    s0 += __shfl_down(s0, off);
    s1 += __shfl_down(s1, off);
  }
  if (lane == 0) {
    const float l0 = s0 + b2[0];
    const float l1 = s1 + b2[1];
    const float mx = fmaxf(l0, l1);
    const float e0 = expf(l0 - mx);
    const float e1 = expf(l1 - mx);
    const float inv = 1.0f / (e0 + e1);
    out[(size_t)gid * 2]     = e0 * inv;
    out[(size_t)gid * 2 + 1] = e1 * inv;
  }
}

// ---------------------------------------------------------------------------
extern "C" void kernel_launch(void* const* d_in, const int* in_sizes, int n_in,
                              void* d_out, int out_size, void* d_ws, size_t ws_size,
                              hipStream_t stream) {
  const float* x  = (const float*)d_in[0];
  const float* Wc = (const float*)d_in[1];
  const float* bc = (const float*)d_in[2];
  const float* W1 = (const float*)d_in[3];
  const float* b1 = (const float*)d_in[4];
  const float* W2 = (const float*)d_in[5];
  const float* b2 = (const float*)d_in[6];
  const int* ei   = (const int*)d_in[7];

  unsigned short* Abf  = (unsigned short*)d_ws;
  unsigned short* W1bf = (unsigned short*)((char*)d_ws + (size_t)67108864);
  float*          h1   = (float*)((char*)d_ws + (size_t)75497472);

  cvt_w1<<<dim3(2048), dim3(256), 0, stream>>>(W1, W1bf);
  gcn_kernel<<<dim3(NGRAPH), dim3(256), 0, stream>>>(x, Wc, bc, ei, Abf);
  lin1_kernel<<<dim3(512), dim3(512), 0, stream>>>(Abf, W1bf, b1, h1);
  lin2_kernel<<<dim3(4096), dim3(256), 0, stream>>>(h1, W2, b2, (float*)d_out);
}

// Round 5
// 231.324 us; speedup vs baseline: 1.6275x; 1.1009x over previous
//
#include <hip/hip_runtime.h>

#define NGRAPH 16384
#define NNODE  32
#define EMB    64
#define HIDDIM 2048
#define ETOT   4194304      // NTOT * 8
#define EPG    256          // edges per graph (contiguous block per graph)

typedef __attribute__((ext_vector_type(8))) short bf16x8_t;
typedef __attribute__((ext_vector_type(8))) unsigned short u16x8_t;
typedef __attribute__((ext_vector_type(4))) float f32x4_t;

__device__ __forceinline__ unsigned short f2bf(float v) {
  unsigned int u = __float_as_uint(v);
  u += 0x7fffu + ((u >> 16) & 1u);
  return (unsigned short)(u >> 16);
}
__device__ __forceinline__ float bf2f(unsigned short u) {
  return __uint_as_float(((unsigned int)u) << 16);
}

#define GLDS(SRC, DST)                                                          \
  __builtin_amdgcn_global_load_lds(                                             \
      (const __attribute__((address_space(1))) void*)(SRC),                     \
      (__attribute__((address_space(3))) void*)(DST), 16, 0, 0)

// ---------------------------------------------------------------------------
// Kernel 1: W1 fp32 -> bf16
// ---------------------------------------------------------------------------
__global__ __launch_bounds__(256) void cvt_w1(const float* __restrict__ W,
                                              unsigned short* __restrict__ Wb) {
  const int i = blockIdx.x * 256 + threadIdx.x;
  const float4* p = (const float4*)W;
  const float4 a = p[2 * i];
  const float4 b = p[2 * i + 1];
  u16x8_t o;
  o[0] = f2bf(a.x); o[1] = f2bf(a.y); o[2] = f2bf(a.z); o[3] = f2bf(a.w);
  o[4] = f2bf(b.x); o[5] = f2bf(b.y); o[6] = f2bf(b.z); o[7] = f2bf(b.w);
  *((u16x8_t*)Wb + i) = o;
}

// ---------------------------------------------------------------------------
// Kernel 2: fused GCNConv + ReLU via MFMA (unchanged)
// ---------------------------------------------------------------------------
__global__ __launch_bounds__(256) void gcn_kernel(const float* __restrict__ x,
                                                  const float* __restrict__ Wc,
                                                  const float* __restrict__ bc,
                                                  const int* __restrict__ ei,
                                                  unsigned short* __restrict__ abf) {
  __shared__ __align__(16) char buf0[8704];
  __shared__ __align__(16) unsigned short xT[64 * 40];
  __shared__ __align__(16) float adjm[NNODE][33];
  __shared__ __align__(16) unsigned short Wcb[64 * 72];
  __shared__ float degs[NNODE];
  __shared__ float dinv[NNODE];
  __shared__ float bcs[EMB];

  float (*xs)[68]      = (float(*)[68])buf0;
  unsigned short* xas  = (unsigned short*)buf0;          // [32][72]
  unsigned short* adjb = (unsigned short*)(buf0 + 4608); // [32][40]

  const int g = blockIdx.x;
  const int t = threadIdx.x;

  {
    const int n = t >> 3, c0 = (t & 7) * 8;
    const float* xp = x + (size_t)g * (NNODE * EMB) + n * EMB + c0;
    *(float4*)&xs[n][c0]     = *(const float4*)xp;
    *(float4*)&xs[n][c0 + 4] = *(const float4*)(xp + 4);
  }
  for (int i = t; i < 512; i += 256) {
    const int r = i >> 3, c = (i & 7) * 8;
    const float4 a = *(const float4*)(Wc + r * EMB + c);
    const float4 b = *(const float4*)(Wc + r * EMB + c + 4);
    u16x8_t o;
    o[0] = f2bf(a.x); o[1] = f2bf(a.y); o[2] = f2bf(a.z); o[3] = f2bf(a.w);
    o[4] = f2bf(b.x); o[5] = f2bf(b.y); o[6] = f2bf(b.z); o[7] = f2bf(b.w);
    *(u16x8_t*)&Wcb[r * 72 + c] = o;
  }
  for (int i = t; i < NNODE * 33; i += 256) (&adjm[0][0])[i] = 0.0f;
  if (t < NNODE) degs[t] = 1.0f;
  if (t < EMB) bcs[t] = bc[t];
  const int sl = ei[(size_t)g * EPG + t] - g * NNODE;
  const int dl = ei[(size_t)ETOT + (size_t)g * EPG + t] - g * NNODE;
  __syncthreads();

  atomicAdd(&degs[dl], 1.0f);
  {
    const int f = t >> 2, s0 = (t & 3) * 8;
    u16x8_t o;
    #pragma unroll
    for (int j = 0; j < 8; ++j) o[j] = f2bf(xs[s0 + j][f]);
    *(u16x8_t*)&xT[f * 40 + s0] = o;
  }
  __syncthreads();
  if (t < NNODE) dinv[t] = rsqrtf(degs[t]);
  __syncthreads();
  atomicAdd(&adjm[dl][sl], dinv[sl] * dinv[dl]);
  if (t < NNODE) atomicAdd(&adjm[t][t], dinv[t] * dinv[t]);
  __syncthreads();
  for (int i = t; i < NNODE * NNODE; i += 256)
    adjb[(i >> 5) * 40 + (i & 31)] = f2bf(adjm[i >> 5][i & 31]);
  __syncthreads();

  const int lane = t & 63, w = t >> 6;
  const int mt = w & 1, nt0 = (w >> 1) * 2;
  const int lr = lane & 15, lk = lane >> 4;
  f32x4_t acc1[2];
  {
    const bf16x8_t af = *(const bf16x8_t*)&adjb[(mt * 16 + lr) * 40 + lk * 8];
    #pragma unroll
    for (int j = 0; j < 2; ++j) {
      const bf16x8_t bfr = *(const bf16x8_t*)&xT[((nt0 + j) * 16 + lr) * 40 + lk * 8];
      acc1[j] = __builtin_amdgcn_mfma_f32_16x16x32_bf16(af, bfr,
                  (f32x4_t){0.f, 0.f, 0.f, 0.f}, 0, 0, 0);
    }
  }
  #pragma unroll
  for (int j = 0; j < 2; ++j)
    #pragma unroll
    for (int r = 0; r < 4; ++r)
      xas[(mt * 16 + lk * 4 + r) * 72 + (nt0 + j) * 16 + lr] = f2bf(acc1[j][r]);
  __syncthreads();

  f32x4_t acc2[2];
  acc2[0] = (f32x4_t){0.f, 0.f, 0.f, 0.f};
  acc2[1] = (f32x4_t){0.f, 0.f, 0.f, 0.f};
  #pragma unroll
  for (int k0 = 0; k0 < EMB; k0 += 32) {
    const bf16x8_t af = *(const bf16x8_t*)&xas[(mt * 16 + lr) * 72 + k0 + lk * 8];
    #pragma unroll
    for (int j = 0; j < 2; ++j) {
      const bf16x8_t bfr = *(const bf16x8_t*)&Wcb[((nt0 + j) * 16 + lr) * 72 + k0 + lk * 8];
      acc2[j] = __builtin_amdgcn_mfma_f32_16x16x32_bf16(af, bfr, acc2[j], 0, 0, 0);
    }
  }
  unsigned short* outs = xT;
  #pragma unroll
  for (int j = 0; j < 2; ++j)
    #pragma unroll
    for (int r = 0; r < 4; ++r) {
      const float v = acc2[j][r] + bcs[(nt0 + j) * 16 + lr];
      outs[(mt * 16 + lk * 4 + r) * 72 + (nt0 + j) * 16 + lr] = f2bf(fmaxf(v, 0.0f));
    }
  __syncthreads();
  {
    const int n = t >> 3, f0 = (t & 7) * 8;
    const u16x8_t o = *(const u16x8_t*)&outs[n * 72 + f0];
    *(u16x8_t*)(abf + (size_t)g * HIDDIM + n * EMB + f0) = o;
  }
}

// ---------------------------------------------------------------------------
// Kernel 3: lin1 GEMM  C = relu(A @ W1^T + b1) -> bf16 out
// 8-phase schedule (unchanged sync); NEW: bm-pinned XCD mapping for L2 A-reuse
// (each XCD owns 8 bm-panels, bn fastest -> concurrent A working set 4MB/XCD),
// bf16 epilogue store (write 131 -> 65.5 MB).
// ---------------------------------------------------------------------------
__global__ __launch_bounds__(512, 1) void lin1_kernel(const unsigned short* __restrict__ A,
                                                      const unsigned short* __restrict__ Bw,
                                                      const float* __restrict__ b1,
                                                      unsigned short* __restrict__ C) {
  __shared__ __align__(16) unsigned short sh[65536];   // 128 KB

  // bm-pinned per XCD: xcd = bid&7 owns bm in [8*xcd, 8*xcd+8), bn fastest.
  // Concurrent 32 blocks/XCD = 4 bm-panels (4MB, L2-fits) x 8 bn (W from L3).
  const int bid = blockIdx.x;
  const int xcd = bid & 7;
  const int g = bid >> 3;                  // 0..63 within XCD
  const int bm = xcd * 8 + (g >> 3);
  const int bn = g & 7;

  const int tid = threadIdx.x;
  const int lane = tid & 63, w = tid >> 6;
  const int wm = w >> 2, wn = w & 3;       // 2 M-waves x 4 N-waves
  const int lr = lane & 15, lk = lane >> 4;

  // staging: half-tile = 128 rows x 64 k; thread t -> rows (t>>3), (t>>3)+64
  const int r0 = tid >> 3;
  const int kge = ((((tid & 7) * 16) ^ ((r0 & 7) << 4)) >> 1);  // swizzled elem
  const unsigned short* gA = A  + (size_t)(bm * 256 + r0) * HIDDIM + kge;
  const unsigned short* gB = Bw + (size_t)(bn * 256 + r0) * HIDDIM + kge;

  auto stage = [&](const unsigned short* gb, int d, int mat, int half, int tile) {
    const unsigned short* s = gb + (size_t)(half * 128) * HIDDIM + tile * 64;
    unsigned short* l = &sh[d * 32768 + mat * 16384 + half * 8192 + tid * 8];
    GLDS(s, l);
    GLDS(s + (size_t)64 * HIDDIM, l + 4096);
  };

  // fragment-read bases (ushort units, relative to dbuf base)
  const int arow = wm * 8192 + lr * 64;                          // A: mat 0, half wm
  const int brow = 16384 + (wn >> 1) * 8192 + ((wn & 1) * 64 + lr) * 64;
  int eoff[2];
  eoff[0] = (lk * 8) ^ ((lr & 7) << 3);
  eoff[1] = (32 + lk * 8) ^ ((lr & 7) << 3);

  f32x4_t acc[8][4];
  #pragma unroll
  for (int i = 0; i < 8; ++i)
    #pragma unroll
    for (int j = 0; j < 4; ++j) acc[i][j] = (f32x4_t){0.f, 0.f, 0.f, 0.f};

  // ---- prologue: tile0 (A+B) -> dbuf0, tile1 B -> dbuf1; gate; barrier
  stage(gA, 0, 0, 0, 0); stage(gA, 0, 0, 1, 0);
  stage(gB, 0, 1, 0, 0); stage(gB, 0, 1, 1, 0);
  stage(gB, 1, 1, 0, 1); stage(gB, 1, 1, 1, 1);
  asm volatile("s_waitcnt vmcnt(4)" ::: "memory");
  __builtin_amdgcn_sched_barrier(0);
  __builtin_amdgcn_s_barrier();

  bf16x8_t af[4][2], bv0[2][2], bv1[2][2];

  for (int it = 0; it < 16; ++it) {
    const int o = 2 * it + 1;
    const bool more = (it < 15);

    #pragma unroll
    for (int half = 0; half < 2; ++half) {     // half 0: dbuf0 (tile 2it), 1: dbuf1
      const int dof = half * 32768;

      // ---- phase 0/4: read A0 quadrant + B0; stage A-half0
      #pragma unroll
      for (int mi = 0; mi < 4; ++mi) {
        af[mi][0] = *(const bf16x8_t*)&sh[dof + arow + mi * 1024 + eoff[0]];
        af[mi][1] = *(const bf16x8_t*)&sh[dof + arow + mi * 1024 + eoff[1]];
      }
      #pragma unroll
      for (int ni = 0; ni < 2; ++ni) {
        bv0[ni][0] = *(const bf16x8_t*)&sh[dof + brow + ni * 1024 + eoff[0]];
        bv0[ni][1] = *(const bf16x8_t*)&sh[dof + brow + ni * 1024 + eoff[1]];
      }
      if (half == 0) stage(gA, 1, 0, 0, o);
      else if (more) stage(gA, 0, 0, 0, o + 1);
      asm volatile("s_waitcnt lgkmcnt(0)" ::: "memory");
      __builtin_amdgcn_sched_barrier(0);
      __builtin_amdgcn_s_barrier();
      __builtin_amdgcn_s_setprio(1);
      #pragma unroll
      for (int kk = 0; kk < 2; ++kk)
        #pragma unroll
        for (int mi = 0; mi < 4; ++mi)
          #pragma unroll
          for (int ni = 0; ni < 2; ++ni)
            acc[mi][ni] = __builtin_amdgcn_mfma_f32_16x16x32_bf16(af[mi][kk], bv0[ni][kk], acc[mi][ni], 0, 0, 0);
      __builtin_amdgcn_s_setprio(0);

      // ---- phase 1/5: read B1; stage A-half1
      #pragma unroll
      for (int ni = 0; ni < 2; ++ni) {
        bv1[ni][0] = *(const bf16x8_t*)&sh[dof + brow + (ni + 2) * 1024 + eoff[0]];
        bv1[ni][1] = *(const bf16x8_t*)&sh[dof + brow + (ni + 2) * 1024 + eoff[1]];
      }
      if (half == 0) stage(gA, 1, 0, 1, o);
      else if (more) stage(gA, 0, 0, 1, o + 1);
      asm volatile("s_waitcnt lgkmcnt(0)" ::: "memory");
      __builtin_amdgcn_sched_barrier(0);
      __builtin_amdgcn_s_barrier();
      __builtin_amdgcn_s_setprio(1);
      #pragma unroll
      for (int kk = 0; kk < 2; ++kk)
        #pragma unroll
        for (int mi = 0; mi < 4; ++mi)
          #pragma unroll
          for (int ni = 0; ni < 2; ++ni)
            acc[mi][ni + 2] = __builtin_amdgcn_mfma_f32_16x16x32_bf16(af[mi][kk], bv1[ni][kk], acc[mi][ni + 2], 0, 0, 0);
      __builtin_amdgcn_s_setprio(0);

      // ---- phase 2/6: read A1 quadrant; stage B-half0 of tile+2
      #pragma unroll
      for (int mi = 0; mi < 4; ++mi) {
        af[mi][0] = *(const bf16x8_t*)&sh[dof + arow + (mi + 4) * 1024 + eoff[0]];
        af[mi][1] = *(const bf16x8_t*)&sh[dof + arow + (mi + 4) * 1024 + eoff[1]];
      }
      if (more) stage(gB, half, 1, 0, (half == 0) ? (o + 1) : (o + 2));
      asm volatile("s_waitcnt lgkmcnt(0)" ::: "memory");
      __builtin_amdgcn_sched_barrier(0);
      __builtin_amdgcn_s_barrier();
      __builtin_amdgcn_s_setprio(1);
      #pragma unroll
      for (int kk = 0; kk < 2; ++kk)
        #pragma unroll
        for (int mi = 0; mi < 4; ++mi)
          #pragma unroll
          for (int ni = 0; ni < 2; ++ni)
            acc[mi + 4][ni + 2] = __builtin_amdgcn_mfma_f32_16x16x32_bf16(af[mi][kk], bv1[ni][kk], acc[mi + 4][ni + 2], 0, 0, 0);
      __builtin_amdgcn_s_setprio(0);

      // ---- phase 3/7: no reads; stage B-half1 of tile+2; vmcnt gate + barrier
      if (more) stage(gB, half, 1, 1, (half == 0) ? (o + 1) : (o + 2));
      asm volatile("s_waitcnt lgkmcnt(0)" ::: "memory");
      if (more) { asm volatile("s_waitcnt vmcnt(4)" ::: "memory"); }
      else      { asm volatile("s_waitcnt vmcnt(0)" ::: "memory"); }
      __builtin_amdgcn_sched_barrier(0);
      __builtin_amdgcn_s_barrier();
      __builtin_amdgcn_s_setprio(1);
      #pragma unroll
      for (int kk = 0; kk < 2; ++kk)
        #pragma unroll
        for (int mi = 0; mi < 4; ++mi)
          #pragma unroll
          for (int ni = 0; ni < 2; ++ni)
            acc[mi + 4][ni] = __builtin_amdgcn_mfma_f32_16x16x32_bf16(af[mi][kk], bv0[ni][kk], acc[mi + 4][ni], 0, 0, 0);
      __builtin_amdgcn_s_setprio(0);
    }
  }

  // ---- epilogue: + b1, relu, bf16 store
  const int crow0 = bm * 256 + wm * 128 + lk * 4;
  const int ccol0 = bn * 256 + wn * 64 + lr;
  float b1v[4];
  #pragma unroll
  for (int ni = 0; ni < 4; ++ni) b1v[ni] = b1[ccol0 + ni * 16];
  #pragma unroll
  for (int mi = 0; mi < 8; ++mi)
    #pragma unroll
    for (int r = 0; r < 4; ++r) {
      unsigned short* cp = C + (size_t)(crow0 + mi * 16 + r) * HIDDIM + ccol0;
      #pragma unroll
      for (int ni = 0; ni < 4; ++ni) {
        const float v = acc[mi][ni][r] + b1v[ni];
        cp[ni * 16] = f2bf(v > 0.0f ? v : 0.0f);
      }
    }
}

// ---------------------------------------------------------------------------
// Kernel 4: lin2 (2 dots of 2048, bf16 h1) + softmax; one wave per graph
// ---------------------------------------------------------------------------
__global__ __launch_bounds__(256) void lin2_kernel(const unsigned short* __restrict__ h1,
                                                   const float* __restrict__ W2,
                                                   const float* __restrict__ b2,
                                                   float* __restrict__ out) {
  const int gid = blockIdx.x * 4 + (threadIdx.x >> 6);
  const int lane = threadIdx.x & 63;
  const u16x8_t* hp = (const u16x8_t*)(h1 + (size_t)gid * HIDDIM);
  const float4* w0 = (const float4*)W2;
  const float4* w1 = (const float4*)(W2 + HIDDIM);
  float s0 = 0.0f, s1 = 0.0f;
  #pragma unroll
  for (int i = 0; i < 4; ++i) {
    const int idx = i * 64 + lane;
    const u16x8_t hv = hp[idx];
    const float4 a0 = w0[2 * idx], a1 = w0[2 * idx + 1];
    const float4 b0 = w1[2 * idx], b1 = w1[2 * idx + 1];
    const float f0 = bf2f(hv[0]), f1 = bf2f(hv[1]), f2 = bf2f(hv[2]), f3 = bf2f(hv[3]);
    const float f4 = bf2f(hv[4]), f5 = bf2f(hv[5]), f6 = bf2f(hv[6]), f7 = bf2f(hv[7]);
    s0 += f0 * a0.x + f1 * a0.y + f2 * a0.z + f3 * a0.w
        + f4 * a1.x + f5 * a1.y + f6 * a1.z + f7 * a1.w;
    s1 += f0 * b0.x + f1 * b0.y + f2 * b0.z + f3 * b0.w
        + f4 * b1.x + f5 * b1.y + f6 * b1.z + f7 * b1.w;
  }
  #pragma unroll
  for (int off = 32; off > 0; off >>= 1) {
    s0 += __shfl_down(s0, off);
    s1 += __shfl_down(s1, off);
  }
  if (lane == 0) {
    const float l0 = s0 + b2[0];
    const float l1 = s1 + b2[1];
    const float mx = fmaxf(l0, l1);
    const float e0 = expf(l0 - mx);
    const float e1 = expf(l1 - mx);
    const float inv = 1.0f / (e0 + e1);
    out[(size_t)gid * 2]     = e0 * inv;
    out[(size_t)gid * 2 + 1] = e1 * inv;
  }
}

// ---------------------------------------------------------------------------
extern "C" void kernel_launch(void* const* d_in, const int* in_sizes, int n_in,
                              void* d_out, int out_size, void* d_ws, size_t ws_size,
                              hipStream_t stream) {
  const float* x  = (const float*)d_in[0];
  const float* Wc = (const float*)d_in[1];
  const float* bc = (const float*)d_in[2];
  const float* W1 = (const float*)d_in[3];
  const float* b1 = (const float*)d_in[4];
  const float* W2 = (const float*)d_in[5];
  const float* b2 = (const float*)d_in[6];
  const int* ei   = (const int*)d_in[7];

  // workspace: [0,64MB) Abf bf16; [64,72MB) W1bf bf16; [72,136MB) h1 bf16
  unsigned short* Abf  = (unsigned short*)d_ws;
  unsigned short* W1bf = (unsigned short*)((char*)d_ws + (size_t)67108864);
  unsigned short* h1   = (unsigned short*)((char*)d_ws + (size_t)75497472);

  cvt_w1<<<dim3(2048), dim3(256), 0, stream>>>(W1, W1bf);
  gcn_kernel<<<dim3(NGRAPH), dim3(256), 0, stream>>>(x, Wc, bc, ei, Abf);
  lin1_kernel<<<dim3(512), dim3(512), 0, stream>>>(Abf, W1bf, b1, h1);
  lin2_kernel<<<dim3(4096), dim3(256), 0, stream>>>(h1, W2, b2, (float*)d_out);
}

// Round 6
// 185.023 us; speedup vs baseline: 2.0348x; 1.2502x over previous
//
#include <hip/hip_runtime.h>

#define NGRAPH 16384
#define NNODE  32
#define EMB    64
#define HIDDIM 2048
#define ETOT   4194304      // NTOT * 8
#define EPG    256          // edges per graph (contiguous block per graph)

typedef __attribute__((ext_vector_type(8))) short bf16x8_t;
typedef __attribute__((ext_vector_type(8))) unsigned short u16x8_t;
typedef __attribute__((ext_vector_type(4))) float f32x4_t;

__device__ __forceinline__ unsigned short f2bf(float v) {
  unsigned int u = __float_as_uint(v);
  u += 0x7fffu + ((u >> 16) & 1u);
  return (unsigned short)(u >> 16);
}
__device__ __forceinline__ float bf2f(unsigned short u) {
  return __uint_as_float(((unsigned int)u) << 16);
}
__device__ __forceinline__ unsigned int cvtpk(float lo, float hi) {
  unsigned int r;
  asm("v_cvt_pk_bf16_f32 %0, %1, %2" : "=v"(r) : "v"(lo), "v"(hi));
  return r;
}
__device__ __forceinline__ bf16x8_t pack8(float4 a, float4 b) {
  union { unsigned int u[4]; bf16x8_t v; } r;
  r.u[0] = cvtpk(a.x, a.y); r.u[1] = cvtpk(a.z, a.w);
  r.u[2] = cvtpk(b.x, b.y); r.u[3] = cvtpk(b.z, b.w);
  return r.v;
}

#define GLDS(SRC, DST)                                                          \
  __builtin_amdgcn_global_load_lds(                                             \
      (const __attribute__((address_space(1))) void*)(SRC),                     \
      (__attribute__((address_space(3))) void*)(DST), 16, 0, 0)

// ---------------------------------------------------------------------------
// Kernel 1: W1 fp32 -> bf16 with column permutation k' = feat*32+node
// (k = node*64+feat). Matches gcn's graph-transposed output layout; the GEMM
// over identically-permuted K is exactly identical.
// ---------------------------------------------------------------------------
__global__ __launch_bounds__(256) void cvt_w1(const float* __restrict__ W,
                                              unsigned short* __restrict__ Wb) {
  __shared__ float row[HIDDIM];
  const int r = blockIdx.x, t = threadIdx.x;
  const float4* p = (const float4*)(W + (size_t)r * HIDDIM);
  *(float4*)&row[t * 8]     = p[t * 2];
  *(float4*)&row[t * 8 + 4] = p[t * 2 + 1];
  __syncthreads();
  const int feat = t >> 2, nb = (t & 3) * 8;   // k' = t*8+j -> feat fixed, node nb+j
  u16x8_t o;
  #pragma unroll
  for (int j = 0; j < 8; ++j) o[j] = f2bf(row[(nb + j) * 64 + feat]);
  *(u16x8_t*)(Wb + (size_t)r * HIDDIM + t * 8) = o;
}

// ---------------------------------------------------------------------------
// Kernel 2: fused GCNConv + ReLU, ONE WAVE PER GRAPH (zero block barriers).
// out = relu( adj @ (x @ Wc^T) + bc ), stored graph-transposed (feat*32+node).
// Per-wave private 10KB LDS slice; all ordering via the wave's in-order DS
// pipe + compiler fences. adjacency = integer LDS-atomic counts -> deg ->
// dinv -> normalized bf16 adj.
// ---------------------------------------------------------------------------
__global__ __launch_bounds__(256, 4) void gcn_kernel(const float* __restrict__ x,
                                                     const float* __restrict__ Wc,
                                                     const float* __restrict__ bc,
                                                     const int* __restrict__ ei,
                                                     unsigned short* __restrict__ abf) {
  __shared__ __align__(16) char smem[40960];     // 4 waves x 10240 B
  const int wv = threadIdx.x >> 6, lane = threadIdx.x & 63;
  const int g = blockIdx.x * 4 + wv;
  char* my = smem + wv * 10240;
  unsigned int*   adjcnt = (unsigned int*)my;            // u32 [32][32], 4096B
  unsigned short* adjb   = (unsigned short*)my;          // bf16 [32][40], 2560B (overlays)
  unsigned short* outT   = (unsigned short*)my;          // bf16 [64][40], 5120B (overlays)
  unsigned short* hT     = (unsigned short*)(my + 5120); // bf16 [64][40], 5120B
  const int lr = lane & 15, lk = lane >> 4;

  // ---- issue x fragment loads early (fp32, straight into MFMA A-frag shape)
  const float* xg = x + (size_t)g * (NNODE * EMB);
  float4 xr[2][2][2];
  #pragma unroll
  for (int mt = 0; mt < 2; ++mt)
    #pragma unroll
    for (int kk = 0; kk < 2; ++kk) {
      const float* p = xg + (mt * 16 + lr) * EMB + kk * 32 + lk * 8;
      xr[mt][kk][0] = *(const float4*)p;
      xr[mt][kk][1] = *(const float4*)(p + 4);
    }

  // ---- edges: 4 per lane
  int sl[4], dl[4];
  #pragma unroll
  for (int j = 0; j < 4; ++j) {
    sl[j] = ei[(size_t)g * EPG + j * 64 + lane] - g * NNODE;
    dl[j] = ei[(size_t)ETOT + (size_t)g * EPG + j * 64 + lane] - g * NNODE;
  }

  // ---- integer adjacency counts
  {
    uint4 z = {0u, 0u, 0u, 0u};
    #pragma unroll
    for (int i = 0; i < 4; ++i) *(uint4*)&adjcnt[lane * 16 + i * 4] = z;
  }
  asm volatile("" ::: "memory");
  #pragma unroll
  for (int j = 0; j < 4; ++j) atomicAdd(&adjcnt[dl[j] * 32 + sl[j]], 1u);
  asm volatile("" ::: "memory");

  // ---- deg -> dinv (lane pair per row), normalized bf16 adjacency
  const int rr = lane >> 1, hh = lane & 1;
  uint4 c[4];
  unsigned int cs = 0;
  #pragma unroll
  for (int i = 0; i < 4; ++i) {
    c[i] = *(const uint4*)&adjcnt[rr * 32 + hh * 16 + i * 4];
    cs += c[i].x + c[i].y + c[i].z + c[i].w;
  }
  cs += (unsigned int)__shfl_xor((int)cs, 1);
  const float dinvr = rsqrtf(1.0f + (float)cs);   // in-degree + self-loop
  asm volatile("" ::: "memory");
  {
    float vals[16];
    #pragma unroll
    for (int i = 0; i < 4; ++i) {
      const unsigned int cc[4] = {c[i].x, c[i].y, c[i].z, c[i].w};
      #pragma unroll
      for (int e = 0; e < 4; ++e) {
        const int s = hh * 16 + i * 4 + e;
        const float ds = __shfl(dinvr, s * 2);
        const float cnt = (float)cc[e] + ((s == rr) ? 1.0f : 0.0f);  // + self-loop
        vals[i * 4 + e] = cnt * dinvr * ds;
      }
    }
    union { unsigned int u[8]; u16x8_t v[2]; } pk;
    #pragma unroll
    for (int i = 0; i < 8; ++i) pk.u[i] = cvtpk(vals[2 * i], vals[2 * i + 1]);
    *(u16x8_t*)&adjb[rr * 40 + hh * 16]     = pk.v[0];
    *(u16x8_t*)&adjb[rr * 40 + hh * 16 + 8] = pk.v[1];
  }

  // ---- transform: h = x @ Wc^T  (M=32, N=64, K=64) — Wc frags direct (L1)
  bf16x8_t xa[2][2];
  #pragma unroll
  for (int mt = 0; mt < 2; ++mt)
    #pragma unroll
    for (int kk = 0; kk < 2; ++kk) xa[mt][kk] = pack8(xr[mt][kk][0], xr[mt][kk][1]);
  f32x4_t hc[2][4];
  #pragma unroll
  for (int mt = 0; mt < 2; ++mt)
    #pragma unroll
    for (int nt = 0; nt < 4; ++nt) hc[mt][nt] = (f32x4_t){0.f, 0.f, 0.f, 0.f};
  #pragma unroll
  for (int nt = 0; nt < 4; ++nt)
    #pragma unroll
    for (int kk = 0; kk < 2; ++kk) {
      const float* p = Wc + (nt * 16 + lr) * EMB + kk * 32 + lk * 8;
      const bf16x8_t wb = pack8(*(const float4*)p, *(const float4*)(p + 4));
      #pragma unroll
      for (int mt = 0; mt < 2; ++mt)
        hc[mt][nt] = __builtin_amdgcn_mfma_f32_16x16x32_bf16(xa[mt][kk], wb, hc[mt][nt], 0, 0, 0);
    }
  // write h^T [feat][node] — acc's 4 rows = 4 consecutive nodes -> packed b64
  #pragma unroll
  for (int mt = 0; mt < 2; ++mt)
    #pragma unroll
    for (int nt = 0; nt < 4; ++nt) {
      uint2 pk;
      pk.x = cvtpk(hc[mt][nt][0], hc[mt][nt][1]);
      pk.y = cvtpk(hc[mt][nt][2], hc[mt][nt][3]);
      *(uint2*)&hT[(nt * 16 + lr) * 40 + mt * 16 + lk * 4] = pk;
    }
  asm volatile("" ::: "memory");

  // ---- aggregate: out = adj @ h  (M=32, N=64, K=32)
  bf16x8_t aj[2];
  #pragma unroll
  for (int mt = 0; mt < 2; ++mt)
    aj[mt] = *(const bf16x8_t*)&adjb[(mt * 16 + lr) * 40 + lk * 8];
  f32x4_t oc[2][4];
  #pragma unroll
  for (int mt = 0; mt < 2; ++mt)
    #pragma unroll
    for (int nt = 0; nt < 4; ++nt) oc[mt][nt] = (f32x4_t){0.f, 0.f, 0.f, 0.f};
  #pragma unroll
  for (int nt = 0; nt < 4; ++nt) {
    const bf16x8_t hb = *(const bf16x8_t*)&hT[(nt * 16 + lr) * 40 + lk * 8];
    #pragma unroll
    for (int mt = 0; mt < 2; ++mt)
      oc[mt][nt] = __builtin_amdgcn_mfma_f32_16x16x32_bf16(aj[mt], hb, oc[mt][nt], 0, 0, 0);
  }
  asm volatile("" ::: "memory");

  // ---- epilogue: +bc, relu, pack -> outT [feat][node] (overlays adj region)
  #pragma unroll
  for (int nt = 0; nt < 4; ++nt) {
    const float bcv = bc[nt * 16 + lr];
    #pragma unroll
    for (int mt = 0; mt < 2; ++mt) {
      float v0 = fmaxf(oc[mt][nt][0] + bcv, 0.0f);
      float v1 = fmaxf(oc[mt][nt][1] + bcv, 0.0f);
      float v2 = fmaxf(oc[mt][nt][2] + bcv, 0.0f);
      float v3 = fmaxf(oc[mt][nt][3] + bcv, 0.0f);
      uint2 pk;
      pk.x = cvtpk(v0, v1);
      pk.y = cvtpk(v2, v3);
      *(uint2*)&outT[(nt * 16 + lr) * 40 + mt * 16 + lk * 4] = pk;
    }
  }
  asm volatile("" ::: "memory");

  // ---- coalesced store: abf[g][k'] with k' = feat*32+node
  unsigned short* og = abf + (size_t)g * HIDDIM;
  #pragma unroll
  for (int j = 0; j < 4; ++j) {
    const int e = lane * 8 + j * 512;
    const int feat = e >> 5, nb = e & 31;
    *(u16x8_t*)(og + e) = *(const u16x8_t*)&outT[feat * 40 + nb];
  }
}

// ---------------------------------------------------------------------------
// Kernel 3: lin1 GEMM  C = relu(A @ W1^T + b1) -> bf16 out  (unchanged)
// ---------------------------------------------------------------------------
__global__ __launch_bounds__(512, 1) void lin1_kernel(const unsigned short* __restrict__ A,
                                                      const unsigned short* __restrict__ Bw,
                                                      const float* __restrict__ b1,
                                                      unsigned short* __restrict__ C) {
  __shared__ __align__(16) unsigned short sh[65536];   // 128 KB

  const int bid = blockIdx.x;
  const int xcd = bid & 7;
  const int g = bid >> 3;                  // 0..63 within XCD
  const int bm = xcd * 8 + (g >> 3);
  const int bn = g & 7;

  const int tid = threadIdx.x;
  const int lane = tid & 63, w = tid >> 6;
  const int wm = w >> 2, wn = w & 3;       // 2 M-waves x 4 N-waves
  const int lr = lane & 15, lk = lane >> 4;

  const int r0 = tid >> 3;
  const int kge = ((((tid & 7) * 16) ^ ((r0 & 7) << 4)) >> 1);  // swizzled elem
  const unsigned short* gA = A  + (size_t)(bm * 256 + r0) * HIDDIM + kge;
  const unsigned short* gB = Bw + (size_t)(bn * 256 + r0) * HIDDIM + kge;

  auto stage = [&](const unsigned short* gb, int d, int mat, int half, int tile) {
    const unsigned short* s = gb + (size_t)(half * 128) * HIDDIM + tile * 64;
    unsigned short* l = &sh[d * 32768 + mat * 16384 + half * 8192 + tid * 8];
    GLDS(s, l);
    GLDS(s + (size_t)64 * HIDDIM, l + 4096);
  };

  const int arow = wm * 8192 + lr * 64;
  const int brow = 16384 + (wn >> 1) * 8192 + ((wn & 1) * 64 + lr) * 64;
  int eoff[2];
  eoff[0] = (lk * 8) ^ ((lr & 7) << 3);
  eoff[1] = (32 + lk * 8) ^ ((lr & 7) << 3);

  f32x4_t acc[8][4];
  #pragma unroll
  for (int i = 0; i < 8; ++i)
    #pragma unroll
    for (int j = 0; j < 4; ++j) acc[i][j] = (f32x4_t){0.f, 0.f, 0.f, 0.f};

  stage(gA, 0, 0, 0, 0); stage(gA, 0, 0, 1, 0);
  stage(gB, 0, 1, 0, 0); stage(gB, 0, 1, 1, 0);
  stage(gB, 1, 1, 0, 1); stage(gB, 1, 1, 1, 1);
  asm volatile("s_waitcnt vmcnt(4)" ::: "memory");
  __builtin_amdgcn_sched_barrier(0);
  __builtin_amdgcn_s_barrier();

  bf16x8_t af[4][2], bv0[2][2], bv1[2][2];

  for (int it = 0; it < 16; ++it) {
    const int o = 2 * it + 1;
    const bool more = (it < 15);

    #pragma unroll
    for (int half = 0; half < 2; ++half) {
      const int dof = half * 32768;

      #pragma unroll
      for (int mi = 0; mi < 4; ++mi) {
        af[mi][0] = *(const bf16x8_t*)&sh[dof + arow + mi * 1024 + eoff[0]];
        af[mi][1] = *(const bf16x8_t*)&sh[dof + arow + mi * 1024 + eoff[1]];
      }
      #pragma unroll
      for (int ni = 0; ni < 2; ++ni) {
        bv0[ni][0] = *(const bf16x8_t*)&sh[dof + brow + ni * 1024 + eoff[0]];
        bv0[ni][1] = *(const bf16x8_t*)&sh[dof + brow + ni * 1024 + eoff[1]];
      }
      if (half == 0) stage(gA, 1, 0, 0, o);
      else if (more) stage(gA, 0, 0, 0, o + 1);
      asm volatile("s_waitcnt lgkmcnt(0)" ::: "memory");
      __builtin_amdgcn_sched_barrier(0);
      __builtin_amdgcn_s_barrier();
      __builtin_amdgcn_s_setprio(1);
      #pragma unroll
      for (int kk = 0; kk < 2; ++kk)
        #pragma unroll
        for (int mi = 0; mi < 4; ++mi)
          #pragma unroll
          for (int ni = 0; ni < 2; ++ni)
            acc[mi][ni] = __builtin_amdgcn_mfma_f32_16x16x32_bf16(af[mi][kk], bv0[ni][kk], acc[mi][ni], 0, 0, 0);
      __builtin_amdgcn_s_setprio(0);

      #pragma unroll
      for (int ni = 0; ni < 2; ++ni) {
        bv1[ni][0] = *(const bf16x8_t*)&sh[dof + brow + (ni + 2) * 1024 + eoff[0]];
        bv1[ni][1] = *(const bf16x8_t*)&sh[dof + brow + (ni + 2) * 1024 + eoff[1]];
      }
      if (half == 0) stage(gA, 1, 0, 1, o);
      else if (more) stage(gA, 0, 0, 1, o + 1);
      asm volatile("s_waitcnt lgkmcnt(0)" ::: "memory");
      __builtin_amdgcn_sched_barrier(0);
      __builtin_amdgcn_s_barrier();
      __builtin_amdgcn_s_setprio(1);
      #pragma unroll
      for (int kk = 0; kk < 2; ++kk)
        #pragma unroll
        for (int mi = 0; mi < 4; ++mi)
          #pragma unroll
          for (int ni = 0; ni < 2; ++ni)
            acc[mi][ni + 2] = __builtin_amdgcn_mfma_f32_16x16x32_bf16(af[mi][kk], bv1[ni][kk], acc[mi][ni + 2], 0, 0, 0);
      __builtin_amdgcn_s_setprio(0);

      #pragma unroll
      for (int mi = 0; mi < 4; ++mi) {
        af[mi][0] = *(const bf16x8_t*)&sh[dof + arow + (mi + 4) * 1024 + eoff[0]];
        af[mi][1] = *(const bf16x8_t*)&sh[dof + arow + (mi + 4) * 1024 + eoff[1]];
      }
      if (more) stage(gB, half, 1, 0, (half == 0) ? (o + 1) : (o + 2));
      asm volatile("s_waitcnt lgkmcnt(0)" ::: "memory");
      __builtin_amdgcn_sched_barrier(0);
      __builtin_amdgcn_s_barrier();
      __builtin_amdgcn_s_setprio(1);
      #pragma unroll
      for (int kk = 0; kk < 2; ++kk)
        #pragma unroll
        for (int mi = 0; mi < 4; ++mi)
          #pragma unroll
          for (int ni = 0; ni < 2; ++ni)
            acc[mi + 4][ni + 2] = __builtin_amdgcn_mfma_f32_16x16x32_bf16(af[mi][kk], bv1[ni][kk], acc[mi + 4][ni + 2], 0, 0, 0);
      __builtin_amdgcn_s_setprio(0);

      if (more) stage(gB, half, 1, 1, (half == 0) ? (o + 1) : (o + 2));
      asm volatile("s_waitcnt lgkmcnt(0)" ::: "memory");
      if (more) { asm volatile("s_waitcnt vmcnt(4)" ::: "memory"); }
      else      { asm volatile("s_waitcnt vmcnt(0)" ::: "memory"); }
      __builtin_amdgcn_sched_barrier(0);
      __builtin_amdgcn_s_barrier();
      __builtin_amdgcn_s_setprio(1);
      #pragma unroll
      for (int kk = 0; kk < 2; ++kk)
        #pragma unroll
        for (int mi = 0; mi < 4; ++mi)
          #pragma unroll
          for (int ni = 0; ni < 2; ++ni)
            acc[mi + 4][ni] = __builtin_amdgcn_mfma_f32_16x16x32_bf16(af[mi][kk], bv0[ni][kk], acc[mi + 4][ni], 0, 0, 0);
      __builtin_amdgcn_s_setprio(0);
    }
  }

  const int crow0 = bm * 256 + wm * 128 + lk * 4;
  const int ccol0 = bn * 256 + wn * 64 + lr;
  float b1v[4];
  #pragma unroll
  for (int ni = 0; ni < 4; ++ni) b1v[ni] = b1[ccol0 + ni * 16];
  #pragma unroll
  for (int mi = 0; mi < 8; ++mi)
    #pragma unroll
    for (int r = 0; r < 4; ++r) {
      unsigned short* cp = C + (size_t)(crow0 + mi * 16 + r) * HIDDIM + ccol0;
      #pragma unroll
      for (int ni = 0; ni < 4; ++ni) {
        const float v = acc[mi][ni][r] + b1v[ni];
        cp[ni * 16] = f2bf(v > 0.0f ? v : 0.0f);
      }
    }
}

// ---------------------------------------------------------------------------
// Kernel 4: lin2 (2 dots of 2048, bf16 h1) + softmax; one wave per graph
// ---------------------------------------------------------------------------
__global__ __launch_bounds__(256) void lin2_kernel(const unsigned short* __restrict__ h1,
                                                   const float* __restrict__ W2,
                                                   const float* __restrict__ b2,
                                                   float* __restrict__ out) {
  const int gid = blockIdx.x * 4 + (threadIdx.x >> 6);
  const int lane = threadIdx.x & 63;
  const u16x8_t* hp = (const u16x8_t*)(h1 + (size_t)gid * HIDDIM);
  const float4* w0 = (const float4*)W2;
  const float4* w1 = (const float4*)(W2 + HIDDIM);
  float s0 = 0.0f, s1 = 0.0f;
  #pragma unroll
  for (int i = 0; i < 4; ++i) {
    const int idx = i * 64 + lane;
    const u16x8_t hv = hp[idx];
    const float4 a0 = w0[2 * idx], a1 = w0[2 * idx + 1];
    const float4 b0 = w1[2 * idx], b1 = w1[2 * idx + 1];
    const float f0 = bf2f(hv[0]), f1 = bf2f(hv[1]), f2 = bf2f(hv[2]), f3 = bf2f(hv[3]);
    const float f4 = bf2f(hv[4]), f5 = bf2f(hv[5]), f6 = bf2f(hv[6]), f7 = bf2f(hv[7]);
    s0 += f0 * a0.x + f1 * a0.y + f2 * a0.z + f3 * a0.w
        + f4 * a1.x + f5 * a1.y + f6 * a1.z + f7 * a1.w;
    s1 += f0 * b0.x + f1 * b0.y + f2 * b0.z + f3 * b0.w
        + f4 * b1.x + f5 * b1.y + f6 * b1.z + f7 * b1.w;
  }
  #pragma unroll
  for (int off = 32; off > 0; off >>= 1) {
    s0 += __shfl_down(s0, off);
    s1 += __shfl_down(s1, off);
  }
  if (lane == 0) {
    const float l0 = s0 + b2[0];
    const float l1 = s1 + b2[1];
    const float mx = fmaxf(l0, l1);
    const float e0 = expf(l0 - mx);
    const float e1 = expf(l1 - mx);
    const float inv = 1.0f / (e0 + e1);
    out[(size_t)gid * 2]     = e0 * inv;
    out[(size_t)gid * 2 + 1] = e1 * inv;
  }
}

// ---------------------------------------------------------------------------
extern "C" void kernel_launch(void* const* d_in, const int* in_sizes, int n_in,
                              void* d_out, int out_size, void* d_ws, size_t ws_size,
                              hipStream_t stream) {
  const float* x  = (const float*)d_in[0];
  const float* Wc = (const float*)d_in[1];
  const float* bc = (const float*)d_in[2];
  const float* W1 = (const float*)d_in[3];
  const float* b1 = (const float*)d_in[4];
  const float* W2 = (const float*)d_in[5];
  const float* b2 = (const float*)d_in[6];
  const int* ei   = (const int*)d_in[7];

  // workspace: [0,64MB) Abf bf16 (graph-transposed); [64,72MB) W1bf bf16
  // (col-permuted to match); [72,136MB) h1 bf16
  unsigned short* Abf  = (unsigned short*)d_ws;
  unsigned short* W1bf = (unsigned short*)((char*)d_ws + (size_t)67108864);
  unsigned short* h1   = (unsigned short*)((char*)d_ws + (size_t)75497472);

  cvt_w1<<<dim3(2048), dim3(256), 0, stream>>>(W1, W1bf);
  gcn_kernel<<<dim3(NGRAPH / 4), dim3(256), 0, stream>>>(x, Wc, bc, ei, Abf);
  lin1_kernel<<<dim3(512), dim3(512), 0, stream>>>(Abf, W1bf, b1, h1);
  lin2_kernel<<<dim3(4096), dim3(256), 0, stream>>>(h1, W2, b2, (float*)d_out);
}